// Round 5
// baseline (3026.251 us; speedup 1.0000x reference)
//
#include <hip/hip_runtime.h>

// ---------------------------------------------------------------------------
// CSBrainAlign: spectral conv -> 4 mamba blocks (fwd chain then bwd chain,
// sequential; workspace ~138 MiB) -> fuse@6 positions -> band/pos/hemi
// -> attn pool -> MLP.
// EXTERNAL dtype: float32 (per reference) for all tensors, int32 for perm.
// Internal activations bf16 (LN-normalized magnitudes), residual H fp32,
// fuse path fp32. Output fp32.
// R3: scan = 1 wave per (bc, 64-chan quarter), no barriers, shfl broadcast.
// R4: scan loads software-pipelined to depth 8 (ring buffer in registers) —
//     fixes in-flight-bytes limit (176 GB/s observed = Little's-law cap at
//     depth 1; depth 8 -> ~1.9 TB/s ceiling).
// ---------------------------------------------------------------------------

typedef unsigned short u16;

#define TT    384      // sequence length N*P
#define BCn   128      // B*C
#define TOKn  49152    // BCn*TT (one chain)

__device__ __forceinline__ float b2f(u16 u) {
  return __uint_as_float(((unsigned)u) << 16);
}
__device__ __forceinline__ u16 f2b(float f) {
  unsigned u = __float_as_uint(f);
  u += 0x7fffu + ((u >> 16) & 1u);   // RNE
  return (u16)(u >> 16);
}
__device__ __forceinline__ float gelu_t(float x) {
  // tanh-approx gelu (jax.nn.gelu default approximate=True)
  float u2 = 1.5957691216057308f * (x + 0.044715f * x * x * x); // 2*sqrt(2/pi)
  float e = __expf(u2);
  float th = 1.f - 2.f / (e + 1.f);
  return 0.5f * x * (1.f + th);
}
__device__ __forceinline__ float silu_f(float x) { return x / (1.f + __expf(-x)); }
__device__ __forceinline__ float softplus_f(float x) {
  return fmaxf(x, 0.f) + log1pf(__expf(-fabsf(x)));
}

__device__ __forceinline__ float block_sum(float v, float* sb) {
  #pragma unroll
  for (int m = 32; m; m >>= 1) v += __shfl_xor(v, m);
  int lane = threadIdx.x & 63, wid = threadIdx.x >> 6;
  if (lane == 0) sb[wid] = v;
  __syncthreads();
  float tot = sb[0] + sb[1] + sb[2] + sb[3];
  __syncthreads();
  return tot;
}

// ---------------------------------------------------------------------------
// Tiled GEMM: out[tok][n] = X[tok][0:K] @ W[0:K][n]
// X: internal bf16. W: external f32. 64x64 tile, 256 thr, 4x4 reg blocking.
// EPI: 0 spectral -> H f32 (+bias; rev!=0 stores time-reversed)
//      1 W_in     -> XZ bf16 (Nw=512)
//      2 W_x      -> XDBL f32 (Nw=40, masked)
//      3 W_out    -> H += acc + bias
// ---------------------------------------------------------------------------
template <int EPI>
__global__ __launch_bounds__(256) void k_gemm(
    const u16* __restrict__ X, const float* __restrict__ W,
    const float* __restrict__ bias, int K, int Nw, int rev,
    float* __restrict__ o0, u16* __restrict__ ob0) {
  __shared__ float Xs[64][68];   // [k][tok], padded
  __shared__ float Ws[64][64];   // [k][n]
  const int tid = threadIdx.x;
  const int tx = tid & 15, ty = tid >> 4;
  const int n0 = blockIdx.x * 64;
  const int tok0 = blockIdx.y * 64;
  float acc[4][4] = {};

  for (int k0 = 0; k0 < K; k0 += 64) {
    #pragma unroll
    for (int r = 0; r < 2; ++r) {
      int idx = tid + r * 256;
      int tokL = idx >> 3, kk = (idx & 7) * 8;
      const u16* p = X + (size_t)(tok0 + tokL) * K + k0 + kk;
      uint4 v = *reinterpret_cast<const uint4*>(p);
      Xs[kk + 0][tokL] = __uint_as_float((v.x & 0xffffu) << 16);
      Xs[kk + 1][tokL] = __uint_as_float(v.x & 0xffff0000u);
      Xs[kk + 2][tokL] = __uint_as_float((v.y & 0xffffu) << 16);
      Xs[kk + 3][tokL] = __uint_as_float(v.y & 0xffff0000u);
      Xs[kk + 4][tokL] = __uint_as_float((v.z & 0xffffu) << 16);
      Xs[kk + 5][tokL] = __uint_as_float(v.z & 0xffff0000u);
      Xs[kk + 6][tokL] = __uint_as_float((v.w & 0xffffu) << 16);
      Xs[kk + 7][tokL] = __uint_as_float(v.w & 0xffff0000u);
    }
    #pragma unroll
    for (int r = 0; r < 2; ++r) {
      int idx = tid + r * 256;
      int kkL = idx >> 3, nn = (idx & 7) * 8;
      int gk = k0 + kkL, gn = n0 + nn;
      if (gn + 8 <= Nw) {
        float4 v0 = *reinterpret_cast<const float4*>(W + (size_t)gk * Nw + gn);
        float4 v1 = *reinterpret_cast<const float4*>(W + (size_t)gk * Nw + gn + 4);
        *reinterpret_cast<float4*>(&Ws[kkL][nn]) = v0;
        *reinterpret_cast<float4*>(&Ws[kkL][nn + 4]) = v1;
      } else {
        #pragma unroll
        for (int j = 0; j < 8; ++j)
          Ws[kkL][nn + j] = (gn + j < Nw) ? W[(size_t)gk * Nw + gn + j] : 0.f;
      }
    }
    __syncthreads();
    #pragma unroll 8
    for (int kk = 0; kk < 64; ++kk) {
      float4 xv = *reinterpret_cast<const float4*>(&Xs[kk][ty * 4]);
      float4 wv = *reinterpret_cast<const float4*>(&Ws[kk][tx * 4]);
      float xa[4] = {xv.x, xv.y, xv.z, xv.w};
      float wa[4] = {wv.x, wv.y, wv.z, wv.w};
      #pragma unroll
      for (int ii = 0; ii < 4; ++ii)
        #pragma unroll
        for (int jj = 0; jj < 4; ++jj)
          acc[ii][jj] = fmaf(xa[ii], wa[jj], acc[ii][jj]);
    }
    __syncthreads();
  }

  #pragma unroll
  for (int ii = 0; ii < 4; ++ii) {
    int tok = tok0 + ty * 4 + ii;
    #pragma unroll
    for (int jj = 0; jj < 4; ++jj) {
      int n = n0 + tx * 4 + jj;
      float v = acc[ii][jj];
      if (EPI == 0) {
        v += bias[n];
        int bc = tok / TT, t = tok % TT;
        int tok2 = rev ? (bc * TT + (TT - 1 - t)) : tok;
        o0[(size_t)tok2 * Nw + n] = v;
      } else if (EPI == 1) {
        ob0[(size_t)tok * Nw + n] = f2b(v);
      } else if (EPI == 2) {
        if (n < Nw) o0[(size_t)tok * Nw + n] = v;
      } else if (EPI == 3) {
        v += bias[n];
        o0[(size_t)tok * Nw + n] += v;
      }
    }
  }
}

// transpose sp_w2 (o,c) -> (c,o) f32 so GEMM sees W[k][n] row-major
__global__ __launch_bounds__(256) void k_w2t(const float* __restrict__ w2,
                                             float* __restrict__ w2t) {
  int i = blockIdx.x * 256 + threadIdx.x;  // 16384
  int o = i >> 7, c = i & 127;
  w2t[c * 128 + o] = w2[o * 128 + c];
}

// spectral conv7 (pad 3) + bias + gelu -> F bf16 [token][c]
__global__ __launch_bounds__(128) void k_spec1(const float* __restrict__ x,
                                               const float* __restrict__ w1,
                                               const float* __restrict__ b1,
                                               u16* __restrict__ F) {
  int token = blockIdx.x;
  int c = threadIdx.x;
  int bc = token / TT, t = token % TT;
  const float* xr = x + (size_t)bc * TT;
  const float* wr = w1 + c * 7;
  float acc = b1[c];
  #pragma unroll
  for (int k = 0; k < 7; ++k) {
    int tt = t + k - 3;
    float xv = (tt >= 0 && tt < TT) ? xr[tt] : 0.f;
    acc += xv * wr[k];
  }
  F[(size_t)token * 128 + c] = f2b(gelu_t(acc));
}

// per-token LayerNorm over D=128: H f32 -> XLN bf16 (weights pre-offset)
__global__ __launch_bounds__(256) void k_ln(const float* __restrict__ H,
                                            const float* __restrict__ gg,
                                            const float* __restrict__ bb,
                                            u16* __restrict__ XLN) {
  int tid = threadIdx.x;
  int lane = tid & 63, wid = tid >> 6;
  int token = blockIdx.x * 4 + wid;
  const float* hr = H + (size_t)token * 128;
  float a = hr[lane], b = hr[lane + 64];
  float s = a + b;
  #pragma unroll
  for (int m = 32; m; m >>= 1) s += __shfl_xor(s, m);
  float mean = s * (1.f / 128.f);
  float d1 = a - mean, d2 = b - mean;
  float q = d1 * d1 + d2 * d2;
  #pragma unroll
  for (int m = 32; m; m >>= 1) q += __shfl_xor(q, m);
  float rs = rsqrtf(q * (1.f / 128.f) + 1e-5f);
  XLN[(size_t)token * 128 + lane] = f2b(d1 * rs * gg[lane] + bb[lane]);
  XLN[(size_t)token * 128 + lane + 64] =
      f2b(d2 * rs * gg[lane + 64] + bb[lane + 64]);
}

// causal depthwise conv (DC=4) + silu : XZ[:, :256] -> XC (4 chan/thread)
__global__ __launch_bounds__(256) void k_conv(const u16* __restrict__ XZ,
                                              const float* __restrict__ cw,
                                              const float* __restrict__ cb,
                                              u16* __restrict__ XC) {
  int idx = blockIdx.x * 256 + threadIdx.x;   // TOKn * 64
  int d4 = idx & 63;
  int tokg = idx >> 6;
  int t = tokg % TT;
  int dbase = d4 * 4;
  const float* cwp = cw + dbase * 4;
  float wv[4][4];
  #pragma unroll
  for (int j = 0; j < 4; ++j)
    #pragma unroll
    for (int k = 0; k < 4; ++k) wv[j][k] = cwp[j * 4 + k];
  float accv[4];
  #pragma unroll
  for (int j = 0; j < 4; ++j) accv[j] = cb[dbase + j];
  #pragma unroll
  for (int k = 0; k < 4; ++k) {
    int tt = t + k - 3;
    if (tt < 0) continue;
    ushort4 xv = *reinterpret_cast<const ushort4*>(
        &XZ[(size_t)(tokg + k - 3) * 512 + dbase]);
    u16 xa[4];
    *reinterpret_cast<ushort4*>(xa) = xv;
    #pragma unroll
    for (int j = 0; j < 4; ++j) accv[j] += b2f(xa[j]) * wv[j][k];
  }
  u16 oa[4];
  #pragma unroll
  for (int j = 0; j < 4; ++j) oa[j] = f2b(silu_f(accv[j]));
  *reinterpret_cast<ushort4*>(&XC[(size_t)tokg * 256 + dbase]) =
      *reinterpret_cast<ushort4*>(oa);
}

// selective scan v3: one WAVE per (bc, 64-channel quarter), 512 blocks,
// no barriers, shfl broadcast; loads software-pipelined to depth PD=8
// (register ring buffer, inner loop unrolled so indices are static).
#define PD 8
__global__ __launch_bounds__(64) void k_scan(
    const float* __restrict__ XDBL, u16* __restrict__ XC,
    const u16* __restrict__ XZ, const float* __restrict__ Wdt,
    const float* __restrict__ bdt, const float* __restrict__ Alog,
    const float* __restrict__ Dpv) {
  int lane = threadIdx.x;              // 0..63
  int q = blockIdx.x & 3;              // channel quarter
  int bc = blockIdx.x >> 2;            // 0..127
  int d = q * 64 + lane;
  float A[16];
  #pragma unroll
  for (int n = 0; n < 16; ++n) A[n] = -__expf(Alog[d * 16 + n]);
  float wdt[8];
  #pragma unroll
  for (int j = 0; j < 8; ++j) wdt[j] = Wdt[j * 256 + d];
  float bd = bdt[d];
  float dpar = Dpv[d];
  float hc[16] = {};
  size_t base = (size_t)bc * TT;
  float xdbB[PD], xcB[PD], zzB[PD];
  #pragma unroll
  for (int p = 0; p < PD; ++p) {
    size_t tk = base + p;
    xdbB[p] = (lane < 40) ? XDBL[tk * 40 + lane] : 0.f;
    xcB[p]  = b2f(XC[tk * 256 + d]);
    zzB[p]  = b2f(XZ[tk * 512 + 256 + d]);
  }
  for (int t0 = 0; t0 < TT; t0 += PD) {
    #pragma unroll
    for (int p = 0; p < PD; ++p) {
      int t = t0 + p;
      size_t tok = base + t;
      float xdb = xdbB[p], xc = xcB[p], zz = zzB[p];
      if (t + PD < TT) {                 // refill slot p for step t+PD
        size_t tk = tok + PD;
        xdbB[p] = (lane < 40) ? XDBL[tk * 40 + lane] : 0.f;
        xcB[p]  = b2f(XC[tk * 256 + d]);
        zzB[p]  = b2f(XZ[tk * 512 + 256 + d]);
      }
      float dtp = bd;
      #pragma unroll
      for (int j = 0; j < 8; ++j) dtp += __shfl(xdb, j) * wdt[j];
      float dt = softplus_f(dtp);
      float dx = dt * xc;
      float y = 0.f;
      #pragma unroll
      for (int n = 0; n < 16; ++n) {
        float e = __expf(A[n] * dt);
        hc[n] = hc[n] * e + dx * __shfl(xdb, 8 + n);
        y += hc[n] * __shfl(xdb, 24 + n);
      }
      y += xc * dpar;
      y *= silu_f(zz);
      XC[tok * 256 + d] = f2b(y);
    }
  }
}

// gather the 6 needed positions into XF[768][256] f32 (half=0 fwd,128 bwd)
__global__ __launch_bounds__(256) void k_gather(const float* __restrict__ H,
                                                float* __restrict__ XF,
                                                int half, int revpos) {
  int i = blockIdx.x * 256 + threadIdx.x;   // 768*128
  int col = i & 127, row = i >> 7;
  int bc = row / 6, u = row % 6;
  int tu = 63 + 64 * u;
  int t = revpos ? (TT - 1 - tu) : tu;
  XF[(size_t)row * 256 + half + col] = H[(size_t)(bc * TT + t) * 128 + col];
}

// fuse: FE[row][d] = XF[row][:] @ fuse_w + fuse_b   (768 rows, K=256)
__global__ __launch_bounds__(128) void k_fuse(const float* __restrict__ XF,
                                              const float* __restrict__ fw,
                                              const float* __restrict__ fb,
                                              float* __restrict__ FE) {
  int row = blockIdx.x;
  int d = threadIdx.x;
  __shared__ float rows[256];
  rows[d] = XF[(size_t)row * 256 + d];
  rows[128 + d] = XF[(size_t)row * 256 + 128 + d];
  __syncthreads();
  float acc = fb[d];
  for (int k = 0; k < 256; ++k) acc += rows[k] * fw[k * 128 + d];
  FE[(size_t)row * 128 + d] = acc;
}

// band projection + event reorder: TO[(bc*9+j)][d]
__global__ __launch_bounds__(128) void k_band(const float* __restrict__ FE,
                                              const float* __restrict__ pw,
                                              const float* __restrict__ pb,
                                              const float* __restrict__ pe,
                                              float* __restrict__ TO) {
  const int u_of[9] = {0, 1, 2, 2, 3, 4, 5, 5, 5};
  const int k_of[9] = {0, 0, 0, 1, 0, 0, 0, 1, 2};
  int bid = blockIdx.x;
  int bc = bid / 9, j = bid % 9;
  int u = u_of[j], kq = k_of[j];
  __shared__ float fs[128];
  int d = threadIdx.x;
  fs[d] = FE[(size_t)(bc * 6 + u) * 128 + d];
  __syncthreads();
  float acc = pb[kq * 128 + d] + pe[kq * 128 + d];
  const float* wp = pw + kq * 16384 + d;
  for (int c = 0; c < 128; ++c) acc += fs[c] * wp[c * 128];
  TO[(size_t)bid * 128 + d] = acc;
}

// depthwise 19x7 pos conv over (C=32, L=9) + residual -> T2 [b][c][l][d]
__global__ __launch_bounds__(256) void k_pos(const float* __restrict__ TO,
                                             const float* __restrict__ pw,
                                             const float* __restrict__ pb,
                                             float* __restrict__ T2) {
  int idx = blockIdx.x * 256 + threadIdx.x;   // 147456
  int d = idx & 127;
  int l = (idx >> 7) % 9;
  int c = (idx / 1152) & 31;
  int b = idx / 36864;
  float acc = 0.f;
  const float* wd = pw + d * 133;
  for (int i = 0; i < 19; ++i) {
    int ci = c + i - 9;
    if (ci < 0 || ci >= 32) continue;
    const float* trow = TO + (size_t)(b * 32 + ci) * 9 * 128 + d;
    #pragma unroll
    for (int jj = 0; jj < 7; ++jj) {
      int lj = l + jj - 3;
      if (lj < 0 || lj >= 9) continue;
      acc += trow[lj * 128] * wd[i * 7 + jj];
    }
  }
  T2[idx] = TO[idx] + acc + pb[d];
}

// hemisphere fusion: concat(own, permuted) @ hemi_w + hemi_b -> FL (flatf)
__global__ __launch_bounds__(128) void k_hemi(const float* __restrict__ T2,
                                              const int* __restrict__ perm,
                                              const float* __restrict__ hw,
                                              const float* __restrict__ hb,
                                              float* __restrict__ FL) {
  int bid = blockIdx.x;   // b*288 + c*9 + l
  int b = bid / 288;
  int c = (bid / 9) % 32;
  int l = bid % 9;
  int pc = perm[b * 32 + c];
  __shared__ float rows[256];
  int d = threadIdx.x;
  rows[d] = T2[((size_t)(b * 32 + c) * 9 + l) * 128 + d];
  rows[128 + d] = T2[((size_t)(b * 32 + pc) * 9 + l) * 128 + d];
  __syncthreads();
  float acc = hb[d];
  for (int k = 0; k < 256; ++k) acc += rows[k] * hw[k * 128 + d];
  FL[(size_t)(b * 32 + c) * 1152 + l * 128 + d] = acc;
}

// attention logits: LN(1152) -> @a_w1(200) -> gelu -> @a_w2 -> logit
__global__ __launch_bounds__(256) void k_attn(
    const float* __restrict__ FL, const float* __restrict__ lg,
    const float* __restrict__ lb, const float* __restrict__ w1,
    const float* __restrict__ b1, const float* __restrict__ w2,
    const float* __restrict__ ab2, float* __restrict__ LO) {
  __shared__ float xn[1152];
  __shared__ float sb[4];
  int row = blockIdx.x;
  int tid = threadIdx.x;
  const float* xr = FL + (size_t)row * 1152;
  float xl[5];
  int cnt = 0;
  float s = 0.f;
  for (int i = tid; i < 1152; i += 256) { xl[cnt] = xr[i]; s += xl[cnt]; ++cnt; }
  float tot = block_sum(s, sb);
  float mean = tot * (1.f / 1152.f);
  float q = 0.f;
  for (int k = 0; k < cnt; ++k) { float dd = xl[k] - mean; q += dd * dd; }
  float qt = block_sum(q, sb);
  float rs = rsqrtf(qt * (1.f / 1152.f) + 1e-5f);
  cnt = 0;
  for (int i = tid; i < 1152; i += 256) {
    xn[i] = (xl[cnt] - mean) * rs * lg[i] + lb[i];
    ++cnt;
  }
  __syncthreads();
  float g = 0.f;
  if (tid < 200) {
    float acc = b1[tid];
    for (int i = 0; i < 1152; ++i) acc += xn[i] * w1[i * 200 + tid];
    g = gelu_t(acc);
  }
  __syncthreads();
  if (tid < 200) xn[tid] = g;
  __syncthreads();
  float s2 = (tid < 200) ? xn[tid] * w2[tid] : 0.f;
  float t2 = block_sum(s2, sb);
  if (tid == 0) LO[row] = t2 + ab2[0];
}

// softmax over C=32 + weighted aggregation of flatf -> AG[b][1152]
__global__ __launch_bounds__(256) void k_smagg(const float* __restrict__ FL,
                                               const float* __restrict__ LO,
                                               float* __restrict__ AG) {
  int b = blockIdx.x;
  int tid = threadIdx.x;
  __shared__ float w[32];
  if (tid == 0) {
    float mx = -1e30f;
    for (int c = 0; c < 32; ++c) mx = fmaxf(mx, LO[b * 32 + c]);
    float sum = 0.f;
    for (int c = 0; c < 32; ++c) { float e = __expf(LO[b * 32 + c] - mx); w[c] = e; sum += e; }
    float inv = 1.f / sum;
    for (int c = 0; c < 32; ++c) w[c] *= inv;
  }
  __syncthreads();
  for (int f = tid; f < 1152; f += 256) {
    float acc = 0.f;
    for (int c = 0; c < 32; ++c) acc += FL[(size_t)(b * 32 + c) * 1152 + f] * w[c];
    AG[b * 1152 + f] = acc;
  }
}

// final LN over agg
__global__ __launch_bounds__(256) void k_lnm(const float* __restrict__ AG,
                                             const float* __restrict__ lg,
                                             const float* __restrict__ lb,
                                             float* __restrict__ AGN) {
  __shared__ float sb[4];
  int b = blockIdx.x;
  int tid = threadIdx.x;
  const float* xr = AG + b * 1152;
  float xl[5];
  int cnt = 0;
  float s = 0.f;
  for (int i = tid; i < 1152; i += 256) { xl[cnt] = xr[i]; s += xl[cnt]; ++cnt; }
  float tot = block_sum(s, sb);
  float mean = tot * (1.f / 1152.f);
  float q = 0.f;
  for (int k = 0; k < cnt; ++k) { float dd = xl[k] - mean; q += dd * dd; }
  float qt = block_sum(q, sb);
  float rs = rsqrtf(qt * (1.f / 1152.f) + 1e-5f);
  cnt = 0;
  for (int i = tid; i < 1152; i += 256) {
    AGN[b * 1152 + i] = (xl[cnt] - mean) * rs * lg[i] + lb[i];
    ++cnt;
  }
}

// g1 = gelu(AGN @ m_w1 + m_b1), 1024 outs per b
__global__ __launch_bounds__(256) void k_g1(const float* __restrict__ AGN,
                                            const float* __restrict__ w1,
                                            const float* __restrict__ b1,
                                            float* __restrict__ G1) {
  int b = blockIdx.y;
  int j = blockIdx.x * 256 + threadIdx.x;   // 1024
  __shared__ float av[1152];
  for (int i = threadIdx.x; i < 1152; i += 256) av[i] = AGN[b * 1152 + i];
  __syncthreads();
  float acc = b1[j];
  for (int i = 0; i < 1152; ++i) acc += av[i] * w1[(size_t)i * 1024 + j];
  G1[b * 1024 + j] = gelu_t(acc);
}

// out = G1 @ m_w2 + m_b2 -> f32 d_out
__global__ __launch_bounds__(256) void k_f3(const float* __restrict__ G1,
                                            const float* __restrict__ w2,
                                            const float* __restrict__ b2v,
                                            float* __restrict__ out) {
  int b = blockIdx.y;
  int o = blockIdx.x * 256 + threadIdx.x;   // 768
  __shared__ float gv[1024];
  for (int i = threadIdx.x; i < 1024; i += 256) gv[i] = G1[b * 1024 + i];
  __syncthreads();
  float acc = b2v[o];
  for (int i = 0; i < 1024; ++i) acc += gv[i] * w2[(size_t)i * 768 + o];
  out[b * 768 + o] = acc;
}

extern "C" void kernel_launch(void* const* d_in, const int* in_sizes, int n_in,
                              void* d_out, int out_size, void* d_ws,
                              size_t ws_size, hipStream_t stream) {
  (void)in_sizes; (void)n_in; (void)out_size; (void)ws_size;
  const float* x      = (const float*)d_in[0];
  const int*   perm   = (const int*)d_in[1];
  const float* sp_w1  = (const float*)d_in[2];
  const float* sp_b1  = (const float*)d_in[3];
  const float* sp_w2  = (const float*)d_in[4];
  const float* sp_b2  = (const float*)d_in[5];
  const float* ln_g   = (const float*)d_in[6];
  const float* ln_b   = (const float*)d_in[7];
  const float* W_in   = (const float*)d_in[8];
  const float* conv_w = (const float*)d_in[9];
  const float* conv_b = (const float*)d_in[10];
  const float* W_x    = (const float*)d_in[11];
  const float* W_dt   = (const float*)d_in[12];
  const float* b_dt   = (const float*)d_in[13];
  const float* A_log  = (const float*)d_in[14];
  const float* Dp     = (const float*)d_in[15];
  const float* W_out  = (const float*)d_in[16];
  const float* b_out  = (const float*)d_in[17];
  const float* fuse_w = (const float*)d_in[18];
  const float* fuse_b = (const float*)d_in[19];
  const float* band_emb = (const float*)d_in[20];
  const float* band_pw  = (const float*)d_in[21];
  const float* band_pb  = (const float*)d_in[22];
  const float* pos_w  = (const float*)d_in[23];
  const float* pos_b  = (const float*)d_in[24];
  const float* hemi_w = (const float*)d_in[25];
  const float* hemi_b = (const float*)d_in[26];
  const float* a_ln_g = (const float*)d_in[27];
  const float* a_ln_b = (const float*)d_in[28];
  const float* a_w1   = (const float*)d_in[29];
  const float* a_b1   = (const float*)d_in[30];
  const float* a_w2   = (const float*)d_in[31];
  const float* a_b2   = (const float*)d_in[32];
  const float* m_ln_g = (const float*)d_in[33];
  const float* m_ln_b = (const float*)d_in[34];
  const float* m_w1   = (const float*)d_in[35];
  const float* m_b1   = (const float*)d_in[36];
  const float* m_w2   = (const float*)d_in[37];
  const float* m_b2   = (const float*)d_in[38];

  char* ws = (char*)d_ws;
  size_t off = 0;
  auto alloc = [&](size_t bytes) -> char* {
    char* p = ws + off;
    off += (bytes + 255) & ~(size_t)255;
    return p;
  };
  // peak ~138 MiB
  float* H    = (float*)alloc((size_t)TOKn * 128 * 4);   // 25.2M
  u16*   F    = (u16*)  alloc((size_t)TOKn * 128 * 2);   // 12.6M
  u16*   XLN  = (u16*)  alloc((size_t)TOKn * 128 * 2);   // 12.6M
  u16*   XZ   = (u16*)  alloc((size_t)TOKn * 512 * 2);   // 50.3M
  u16*   XC   = (u16*)  alloc((size_t)TOKn * 256 * 2);   // 25.2M
  float* XDBL = (float*)alloc((size_t)TOKn * 40 * 4);    // 7.9M
  float* W2T  = (float*)alloc(16384 * 4);
  float* XF   = (float*)alloc(768 * 256 * 4);
  float* FE   = (float*)alloc(768 * 128 * 4);
  float* TO   = (float*)alloc(1152 * 128 * 4);
  float* T2v  = (float*)alloc(147456 * 4);
  float* FL   = (float*)alloc(147456 * 4);
  float* LO   = (float*)alloc(128 * 4);
  float* AG   = (float*)alloc(4 * 1152 * 4);
  float* AGN  = (float*)alloc(4 * 1152 * 4);
  float* G1v  = (float*)alloc(4 * 1024 * 4);

  // spectral front-end
  k_w2t<<<dim3(64), dim3(256), 0, stream>>>(sp_w2, W2T);
  k_spec1<<<dim3(TOKn), dim3(128), 0, stream>>>(x, sp_w1, sp_b1, F);

  auto mamba_round = [&](int blk) {
    k_ln<<<dim3(TOKn / 4), dim3(256), 0, stream>>>(
        H, ln_g + blk * 128, ln_b + blk * 128, XLN);
    k_gemm<1><<<dim3(8, TOKn / 64), dim3(256), 0, stream>>>(
        XLN, W_in + (size_t)blk * 65536, nullptr, 128, 512, 0, nullptr, XZ);
    k_conv<<<dim3(TOKn * 64 / 256), dim3(256), 0, stream>>>(
        XZ, conv_w + blk * 1024, conv_b + blk * 256, XC);
    k_gemm<2><<<dim3(1, TOKn / 64), dim3(256), 0, stream>>>(
        XC, W_x + (size_t)blk * 10240, nullptr, 256, 40, 0, XDBL, nullptr);
    k_scan<<<dim3(BCn * 4), dim3(64), 0, stream>>>(
        XDBL, XC, XZ, W_dt + blk * 2048, b_dt + blk * 256,
        A_log + blk * 4096, Dp + blk * 256);
    k_gemm<3><<<dim3(2, TOKn / 64), dim3(256), 0, stream>>>(
        XC, W_out + (size_t)blk * 32768, b_out + blk * 128, 256, 128, 0,
        H, nullptr);
  };

  // forward chain (blocks 0,1)
  k_gemm<0><<<dim3(2, TOKn / 64), dim3(256), 0, stream>>>(
      F, W2T, sp_b2, 128, 128, 0, H, nullptr);
  mamba_round(0);
  mamba_round(1);
  k_gather<<<dim3(384), dim3(256), 0, stream>>>(H, XF, 0, 0);

  // backward chain (blocks 2,3) on time-reversed h
  k_gemm<0><<<dim3(2, TOKn / 64), dim3(256), 0, stream>>>(
      F, W2T, sp_b2, 128, 128, 1, H, nullptr);
  mamba_round(2);
  mamba_round(3);
  k_gather<<<dim3(384), dim3(256), 0, stream>>>(H, XF, 128, 1);

  // tail
  k_fuse<<<dim3(768), dim3(128), 0, stream>>>(XF, fuse_w, fuse_b, FE);
  k_band<<<dim3(1152), dim3(128), 0, stream>>>(FE, band_pw, band_pb, band_emb, TO);
  k_pos<<<dim3(576), dim3(256), 0, stream>>>(TO, pos_w, pos_b, T2v);
  k_hemi<<<dim3(1152), dim3(128), 0, stream>>>(T2v, perm, hemi_w, hemi_b, FL);
  k_attn<<<dim3(128), dim3(256), 0, stream>>>(FL, a_ln_g, a_ln_b, a_w1, a_b1,
                                              a_w2, a_b2, LO);
  k_smagg<<<dim3(4), dim3(256), 0, stream>>>(FL, LO, AG);
  k_lnm<<<dim3(4), dim3(256), 0, stream>>>(AG, m_ln_g, m_ln_b, AGN);
  k_g1<<<dim3(4, 4), dim3(256), 0, stream>>>(AGN, m_w1, m_b1, G1v);
  k_f3<<<dim3(3, 4), dim3(256), 0, stream>>>(G1v, m_w2, m_b2, (float*)d_out);
}

// Round 6
// 2583.779 us; speedup vs baseline: 1.1712x; 1.1712x over previous
//
#include <hip/hip_runtime.h>

// ---------------------------------------------------------------------------
// CSBrainAlign: spectral conv -> 4 mamba blocks (fwd chain then bwd chain,
// sequential; workspace ~138 MiB) -> fuse@6 positions -> band/pos/hemi
// -> attn pool -> MLP.
// EXTERNAL dtype: float32 (per reference), int32 perm. Internal acts bf16,
// residual H fp32, fuse path fp32, output fp32.
// R3: scan = wave-parallel, shfl broadcast (barrier-free compute).
// R4: register ring-buffer pipeline — FAILED (compiler serialized; 139 GB/s).
// R5: scan = block per bc, LDS-staged 32-step chunks, double-buffered:
//     issue next-chunk global loads -> scan current chunk from LDS (hides
//     latency with compute) -> ds_write staged regs -> barrier. 12 barriers
//     total; coalesced 16B staging loads.
// ---------------------------------------------------------------------------

typedef unsigned short u16;

#define TT    384      // sequence length N*P
#define BCn   128      // B*C
#define TOKn  49152    // BCn*TT (one chain)
#define CH    32       // scan chunk (steps)
#define NCH   (TT/CH)  // 12 chunks

__device__ __forceinline__ float b2f(u16 u) {
  return __uint_as_float(((unsigned)u) << 16);
}
__device__ __forceinline__ u16 f2b(float f) {
  unsigned u = __float_as_uint(f);
  u += 0x7fffu + ((u >> 16) & 1u);   // RNE
  return (u16)(u >> 16);
}
__device__ __forceinline__ float gelu_t(float x) {
  float u2 = 1.5957691216057308f * (x + 0.044715f * x * x * x);
  float e = __expf(u2);
  float th = 1.f - 2.f / (e + 1.f);
  return 0.5f * x * (1.f + th);
}
__device__ __forceinline__ float silu_f(float x) { return x / (1.f + __expf(-x)); }
__device__ __forceinline__ float softplus_f(float x) {
  return fmaxf(x, 0.f) + log1pf(__expf(-fabsf(x)));
}

__device__ __forceinline__ float block_sum(float v, float* sb) {
  #pragma unroll
  for (int m = 32; m; m >>= 1) v += __shfl_xor(v, m);
  int lane = threadIdx.x & 63, wid = threadIdx.x >> 6;
  if (lane == 0) sb[wid] = v;
  __syncthreads();
  float tot = sb[0] + sb[1] + sb[2] + sb[3];
  __syncthreads();
  return tot;
}

// ---------------------------------------------------------------------------
// Tiled GEMM: out[tok][n] = X[tok][0:K] @ W[0:K][n]
// X: internal bf16. W: external f32. 64x64 tile, 256 thr, 4x4 reg blocking.
// EPI: 0 spectral -> H f32 (+bias; rev!=0 stores time-reversed)
//      1 W_in     -> XZ bf16 (Nw=512)
//      2 W_x      -> XDBL f32 (Nw=40, masked)
//      3 W_out    -> H += acc + bias
// ---------------------------------------------------------------------------
template <int EPI>
__global__ __launch_bounds__(256) void k_gemm(
    const u16* __restrict__ X, const float* __restrict__ W,
    const float* __restrict__ bias, int K, int Nw, int rev,
    float* __restrict__ o0, u16* __restrict__ ob0) {
  __shared__ float Xs[64][68];   // [k][tok], padded
  __shared__ float Ws[64][64];   // [k][n]
  const int tid = threadIdx.x;
  const int tx = tid & 15, ty = tid >> 4;
  const int n0 = blockIdx.x * 64;
  const int tok0 = blockIdx.y * 64;
  float acc[4][4] = {};

  for (int k0 = 0; k0 < K; k0 += 64) {
    #pragma unroll
    for (int r = 0; r < 2; ++r) {
      int idx = tid + r * 256;
      int tokL = idx >> 3, kk = (idx & 7) * 8;
      const u16* p = X + (size_t)(tok0 + tokL) * K + k0 + kk;
      uint4 v = *reinterpret_cast<const uint4*>(p);
      Xs[kk + 0][tokL] = __uint_as_float((v.x & 0xffffu) << 16);
      Xs[kk + 1][tokL] = __uint_as_float(v.x & 0xffff0000u);
      Xs[kk + 2][tokL] = __uint_as_float((v.y & 0xffffu) << 16);
      Xs[kk + 3][tokL] = __uint_as_float(v.y & 0xffff0000u);
      Xs[kk + 4][tokL] = __uint_as_float((v.z & 0xffffu) << 16);
      Xs[kk + 5][tokL] = __uint_as_float(v.z & 0xffff0000u);
      Xs[kk + 6][tokL] = __uint_as_float((v.w & 0xffffu) << 16);
      Xs[kk + 7][tokL] = __uint_as_float(v.w & 0xffff0000u);
    }
    #pragma unroll
    for (int r = 0; r < 2; ++r) {
      int idx = tid + r * 256;
      int kkL = idx >> 3, nn = (idx & 7) * 8;
      int gk = k0 + kkL, gn = n0 + nn;
      if (gn + 8 <= Nw) {
        float4 v0 = *reinterpret_cast<const float4*>(W + (size_t)gk * Nw + gn);
        float4 v1 = *reinterpret_cast<const float4*>(W + (size_t)gk * Nw + gn + 4);
        *reinterpret_cast<float4*>(&Ws[kkL][nn]) = v0;
        *reinterpret_cast<float4*>(&Ws[kkL][nn + 4]) = v1;
      } else {
        #pragma unroll
        for (int j = 0; j < 8; ++j)
          Ws[kkL][nn + j] = (gn + j < Nw) ? W[(size_t)gk * Nw + gn + j] : 0.f;
      }
    }
    __syncthreads();
    #pragma unroll 8
    for (int kk = 0; kk < 64; ++kk) {
      float4 xv = *reinterpret_cast<const float4*>(&Xs[kk][ty * 4]);
      float4 wv = *reinterpret_cast<const float4*>(&Ws[kk][tx * 4]);
      float xa[4] = {xv.x, xv.y, xv.z, xv.w};
      float wa[4] = {wv.x, wv.y, wv.z, wv.w};
      #pragma unroll
      for (int ii = 0; ii < 4; ++ii)
        #pragma unroll
        for (int jj = 0; jj < 4; ++jj)
          acc[ii][jj] = fmaf(xa[ii], wa[jj], acc[ii][jj]);
    }
    __syncthreads();
  }

  #pragma unroll
  for (int ii = 0; ii < 4; ++ii) {
    int tok = tok0 + ty * 4 + ii;
    #pragma unroll
    for (int jj = 0; jj < 4; ++jj) {
      int n = n0 + tx * 4 + jj;
      float v = acc[ii][jj];
      if (EPI == 0) {
        v += bias[n];
        int bc = tok / TT, t = tok % TT;
        int tok2 = rev ? (bc * TT + (TT - 1 - t)) : tok;
        o0[(size_t)tok2 * Nw + n] = v;
      } else if (EPI == 1) {
        ob0[(size_t)tok * Nw + n] = f2b(v);
      } else if (EPI == 2) {
        if (n < Nw) o0[(size_t)tok * Nw + n] = v;
      } else if (EPI == 3) {
        v += bias[n];
        o0[(size_t)tok * Nw + n] += v;
      }
    }
  }
}

// transpose sp_w2 (o,c) -> (c,o) f32 so GEMM sees W[k][n] row-major
__global__ __launch_bounds__(256) void k_w2t(const float* __restrict__ w2,
                                             float* __restrict__ w2t) {
  int i = blockIdx.x * 256 + threadIdx.x;  // 16384
  int o = i >> 7, c = i & 127;
  w2t[c * 128 + o] = w2[o * 128 + c];
}

// spectral conv7 (pad 3) + bias + gelu -> F bf16 [token][c]
__global__ __launch_bounds__(128) void k_spec1(const float* __restrict__ x,
                                               const float* __restrict__ w1,
                                               const float* __restrict__ b1,
                                               u16* __restrict__ F) {
  int token = blockIdx.x;
  int c = threadIdx.x;
  int bc = token / TT, t = token % TT;
  const float* xr = x + (size_t)bc * TT;
  const float* wr = w1 + c * 7;
  float acc = b1[c];
  #pragma unroll
  for (int k = 0; k < 7; ++k) {
    int tt = t + k - 3;
    float xv = (tt >= 0 && tt < TT) ? xr[tt] : 0.f;
    acc += xv * wr[k];
  }
  F[(size_t)token * 128 + c] = f2b(gelu_t(acc));
}

// per-token LayerNorm over D=128: H f32 -> XLN bf16 (weights pre-offset)
__global__ __launch_bounds__(256) void k_ln(const float* __restrict__ H,
                                            const float* __restrict__ gg,
                                            const float* __restrict__ bb,
                                            u16* __restrict__ XLN) {
  int tid = threadIdx.x;
  int lane = tid & 63, wid = tid >> 6;
  int token = blockIdx.x * 4 + wid;
  const float* hr = H + (size_t)token * 128;
  float a = hr[lane], b = hr[lane + 64];
  float s = a + b;
  #pragma unroll
  for (int m = 32; m; m >>= 1) s += __shfl_xor(s, m);
  float mean = s * (1.f / 128.f);
  float d1 = a - mean, d2 = b - mean;
  float q = d1 * d1 + d2 * d2;
  #pragma unroll
  for (int m = 32; m; m >>= 1) q += __shfl_xor(q, m);
  float rs = rsqrtf(q * (1.f / 128.f) + 1e-5f);
  XLN[(size_t)token * 128 + lane] = f2b(d1 * rs * gg[lane] + bb[lane]);
  XLN[(size_t)token * 128 + lane + 64] =
      f2b(d2 * rs * gg[lane + 64] + bb[lane + 64]);
}

// causal depthwise conv (DC=4) + silu : XZ[:, :256] -> XC (4 chan/thread)
__global__ __launch_bounds__(256) void k_conv(const u16* __restrict__ XZ,
                                              const float* __restrict__ cw,
                                              const float* __restrict__ cb,
                                              u16* __restrict__ XC) {
  int idx = blockIdx.x * 256 + threadIdx.x;   // TOKn * 64
  int d4 = idx & 63;
  int tokg = idx >> 6;
  int t = tokg % TT;
  int dbase = d4 * 4;
  const float* cwp = cw + dbase * 4;
  float wv[4][4];
  #pragma unroll
  for (int j = 0; j < 4; ++j)
    #pragma unroll
    for (int k = 0; k < 4; ++k) wv[j][k] = cwp[j * 4 + k];
  float accv[4];
  #pragma unroll
  for (int j = 0; j < 4; ++j) accv[j] = cb[dbase + j];
  #pragma unroll
  for (int k = 0; k < 4; ++k) {
    int tt = t + k - 3;
    if (tt < 0) continue;
    ushort4 xv = *reinterpret_cast<const ushort4*>(
        &XZ[(size_t)(tokg + k - 3) * 512 + dbase]);
    u16 xa[4];
    *reinterpret_cast<ushort4*>(xa) = xv;
    #pragma unroll
    for (int j = 0; j < 4; ++j) accv[j] += b2f(xa[j]) * wv[j][k];
  }
  u16 oa[4];
  #pragma unroll
  for (int j = 0; j < 4; ++j) oa[j] = f2b(silu_f(accv[j]));
  *reinterpret_cast<ushort4*>(&XC[(size_t)tokg * 256 + dbase]) =
      *reinterpret_cast<ushort4*>(oa);
}

// selective scan v4: one block (256 thr = 4 waves) per bc. Time chunked by
// CH=32; chunk staged via registers -> LDS, double-buffered; next-chunk
// global loads issued BEFORE scanning current chunk (latency hidden by
// compute), ds_write after, one barrier per chunk.
__global__ __launch_bounds__(256) void k_scan(
    const float* __restrict__ XDBL, u16* __restrict__ XC,
    const u16* __restrict__ XZ, const float* __restrict__ Wdt,
    const float* __restrict__ bdt, const float* __restrict__ Alog,
    const float* __restrict__ Dpv) {
  __shared__ u16  xcs[2][CH * 256];   // 2 x 16 KB
  __shared__ u16  zs [2][CH * 256];   // 2 x 16 KB
  __shared__ float xds[2][CH * 40];   // 2 x 5 KB
  const int tid = threadIdx.x;        // channel d
  const int lane = tid & 63;
  const int bc = blockIdx.x;
  const int d = tid;

  float A[16];
  #pragma unroll
  for (int n = 0; n < 16; ++n) A[n] = -__expf(Alog[d * 16 + n]);
  float wdt[8];
  #pragma unroll
  for (int j = 0; j < 8; ++j) wdt[j] = Wdt[j * 256 + d];
  const float bd = bdt[d];
  const float dpar = Dpv[d];
  float hc[16] = {};

  const size_t base = (size_t)bc * TT;
  const u16*   xcg = XC + base * 256;
  const u16*   zg  = XZ + base * 512 + 256;
  const float* xdg = XDBL + base * 40;
  u16* outg = XC + base * 256;

  uint4 cxc[4], cz[4];  float cxd[5];   // staged regs for next chunk

  auto issue_loads = [&](int c) {
    const u16* px = xcg + (size_t)c * CH * 256;
    #pragma unroll
    for (int r = 0; r < 4; ++r)
      cxc[r] = *reinterpret_cast<const uint4*>(px + r * 2048 + tid * 8);
    #pragma unroll
    for (int r = 0; r < 4; ++r) {
      int s = r * 8 + (tid >> 5);
      cz[r] = *reinterpret_cast<const uint4*>(
          zg + (size_t)(c * CH + s) * 512 + (tid & 31) * 8);
    }
    const float* pd = xdg + (size_t)c * CH * 40;
    #pragma unroll
    for (int r = 0; r < 5; ++r) cxd[r] = pd[r * 256 + tid];
  };
  auto write_lds = [&](int b) {
    #pragma unroll
    for (int r = 0; r < 4; ++r)
      *reinterpret_cast<uint4*>(&xcs[b][r * 2048 + tid * 8]) = cxc[r];
    #pragma unroll
    for (int r = 0; r < 4; ++r) {
      int s = r * 8 + (tid >> 5);
      *reinterpret_cast<uint4*>(&zs[b][s * 256 + (tid & 31) * 8]) = cz[r];
    }
    #pragma unroll
    for (int r = 0; r < 5; ++r) xds[b][r * 256 + tid] = cxd[r];
  };

  issue_loads(0);
  write_lds(0);
  __syncthreads();

  for (int c = 0; c < NCH; ++c) {
    int b = c & 1;
    if (c + 1 < NCH) issue_loads(c + 1);
    // scan chunk c from LDS buffer b
    size_t tok = base + (size_t)c * CH;
    for (int t = 0; t < CH; ++t, ++tok) {
      float xdb = (lane < 40) ? xds[b][t * 40 + lane] : 0.f;
      float xc = b2f(xcs[b][t * 256 + d]);
      float zz = b2f(zs[b][t * 256 + d]);
      float dtp = bd;
      #pragma unroll
      for (int j = 0; j < 8; ++j) dtp += __shfl(xdb, j) * wdt[j];
      float dt = softplus_f(dtp);
      float dx = dt * xc;
      float y = 0.f;
      #pragma unroll
      for (int n = 0; n < 16; ++n) {
        float e = __expf(A[n] * dt);
        hc[n] = hc[n] * e + dx * __shfl(xdb, 8 + n);
        y += hc[n] * __shfl(xdb, 24 + n);
      }
      y += xc * dpar;
      y *= silu_f(zz);
      outg[tok * 256 + d - base * 256] = f2b(y);
    }
    if (c + 1 < NCH) write_lds(b ^ 1);
    __syncthreads();
  }
}

// gather the 6 needed positions into XF[768][256] f32 (half=0 fwd,128 bwd)
__global__ __launch_bounds__(256) void k_gather(const float* __restrict__ H,
                                                float* __restrict__ XF,
                                                int half, int revpos) {
  int i = blockIdx.x * 256 + threadIdx.x;   // 768*128
  int col = i & 127, row = i >> 7;
  int bc = row / 6, u = row % 6;
  int tu = 63 + 64 * u;
  int t = revpos ? (TT - 1 - tu) : tu;
  XF[(size_t)row * 256 + half + col] = H[(size_t)(bc * TT + t) * 128 + col];
}

// fuse: FE[row][d] = XF[row][:] @ fuse_w + fuse_b   (768 rows, K=256)
__global__ __launch_bounds__(128) void k_fuse(const float* __restrict__ XF,
                                              const float* __restrict__ fw,
                                              const float* __restrict__ fb,
                                              float* __restrict__ FE) {
  int row = blockIdx.x;
  int d = threadIdx.x;
  __shared__ float rows[256];
  rows[d] = XF[(size_t)row * 256 + d];
  rows[128 + d] = XF[(size_t)row * 256 + 128 + d];
  __syncthreads();
  float acc = fb[d];
  for (int k = 0; k < 256; ++k) acc += rows[k] * fw[k * 128 + d];
  FE[(size_t)row * 128 + d] = acc;
}

// band projection + event reorder: TO[(bc*9+j)][d]
__global__ __launch_bounds__(128) void k_band(const float* __restrict__ FE,
                                              const float* __restrict__ pw,
                                              const float* __restrict__ pb,
                                              const float* __restrict__ pe,
                                              float* __restrict__ TO) {
  const int u_of[9] = {0, 1, 2, 2, 3, 4, 5, 5, 5};
  const int k_of[9] = {0, 0, 0, 1, 0, 0, 0, 1, 2};
  int bid = blockIdx.x;
  int bc = bid / 9, j = bid % 9;
  int u = u_of[j], kq = k_of[j];
  __shared__ float fs[128];
  int d = threadIdx.x;
  fs[d] = FE[(size_t)(bc * 6 + u) * 128 + d];
  __syncthreads();
  float acc = pb[kq * 128 + d] + pe[kq * 128 + d];
  const float* wp = pw + kq * 16384 + d;
  for (int c = 0; c < 128; ++c) acc += fs[c] * wp[c * 128];
  TO[(size_t)bid * 128 + d] = acc;
}

// depthwise 19x7 pos conv over (C=32, L=9) + residual -> T2 [b][c][l][d]
__global__ __launch_bounds__(256) void k_pos(const float* __restrict__ TO,
                                             const float* __restrict__ pw,
                                             const float* __restrict__ pb,
                                             float* __restrict__ T2) {
  int idx = blockIdx.x * 256 + threadIdx.x;   // 147456
  int d = idx & 127;
  int l = (idx >> 7) % 9;
  int c = (idx / 1152) & 31;
  int b = idx / 36864;
  float acc = 0.f;
  const float* wd = pw + d * 133;
  for (int i = 0; i < 19; ++i) {
    int ci = c + i - 9;
    if (ci < 0 || ci >= 32) continue;
    const float* trow = TO + (size_t)(b * 32 + ci) * 9 * 128 + d;
    #pragma unroll
    for (int jj = 0; jj < 7; ++jj) {
      int lj = l + jj - 3;
      if (lj < 0 || lj >= 9) continue;
      acc += trow[lj * 128] * wd[i * 7 + jj];
    }
  }
  T2[idx] = TO[idx] + acc + pb[d];
}

// hemisphere fusion: concat(own, permuted) @ hemi_w + hemi_b -> FL (flatf)
__global__ __launch_bounds__(128) void k_hemi(const float* __restrict__ T2,
                                              const int* __restrict__ perm,
                                              const float* __restrict__ hw,
                                              const float* __restrict__ hb,
                                              float* __restrict__ FL) {
  int bid = blockIdx.x;   // b*288 + c*9 + l
  int b = bid / 288;
  int c = (bid / 9) % 32;
  int l = bid % 9;
  int pc = perm[b * 32 + c];
  __shared__ float rows[256];
  int d = threadIdx.x;
  rows[d] = T2[((size_t)(b * 32 + c) * 9 + l) * 128 + d];
  rows[128 + d] = T2[((size_t)(b * 32 + pc) * 9 + l) * 128 + d];
  __syncthreads();
  float acc = hb[d];
  for (int k = 0; k < 256; ++k) acc += rows[k] * hw[k * 128 + d];
  FL[(size_t)(b * 32 + c) * 1152 + l * 128 + d] = acc;
}

// attention logits: LN(1152) -> @a_w1(200) -> gelu -> @a_w2 -> logit
__global__ __launch_bounds__(256) void k_attn(
    const float* __restrict__ FL, const float* __restrict__ lg,
    const float* __restrict__ lb, const float* __restrict__ w1,
    const float* __restrict__ b1, const float* __restrict__ w2,
    const float* __restrict__ ab2, float* __restrict__ LO) {
  __shared__ float xn[1152];
  __shared__ float sb[4];
  int row = blockIdx.x;
  int tid = threadIdx.x;
  const float* xr = FL + (size_t)row * 1152;
  float xl[5];
  int cnt = 0;
  float s = 0.f;
  for (int i = tid; i < 1152; i += 256) { xl[cnt] = xr[i]; s += xl[cnt]; ++cnt; }
  float tot = block_sum(s, sb);
  float mean = tot * (1.f / 1152.f);
  float q = 0.f;
  for (int k = 0; k < cnt; ++k) { float dd = xl[k] - mean; q += dd * dd; }
  float qt = block_sum(q, sb);
  float rs = rsqrtf(qt * (1.f / 1152.f) + 1e-5f);
  cnt = 0;
  for (int i = tid; i < 1152; i += 256) {
    xn[i] = (xl[cnt] - mean) * rs * lg[i] + lb[i];
    ++cnt;
  }
  __syncthreads();
  float g = 0.f;
  if (tid < 200) {
    float acc = b1[tid];
    for (int i = 0; i < 1152; ++i) acc += xn[i] * w1[i * 200 + tid];
    g = gelu_t(acc);
  }
  __syncthreads();
  if (tid < 200) xn[tid] = g;
  __syncthreads();
  float s2 = (tid < 200) ? xn[tid] * w2[tid] : 0.f;
  float t2 = block_sum(s2, sb);
  if (tid == 0) LO[row] = t2 + ab2[0];
}

// softmax over C=32 + weighted aggregation of flatf -> AG[b][1152]
__global__ __launch_bounds__(256) void k_smagg(const float* __restrict__ FL,
                                               const float* __restrict__ LO,
                                               float* __restrict__ AG) {
  int b = blockIdx.x;
  int tid = threadIdx.x;
  __shared__ float w[32];
  if (tid == 0) {
    float mx = -1e30f;
    for (int c = 0; c < 32; ++c) mx = fmaxf(mx, LO[b * 32 + c]);
    float sum = 0.f;
    for (int c = 0; c < 32; ++c) { float e = __expf(LO[b * 32 + c] - mx); w[c] = e; sum += e; }
    float inv = 1.f / sum;
    for (int c = 0; c < 32; ++c) w[c] *= inv;
  }
  __syncthreads();
  for (int f = tid; f < 1152; f += 256) {
    float acc = 0.f;
    for (int c = 0; c < 32; ++c) acc += FL[(size_t)(b * 32 + c) * 1152 + f] * w[c];
    AG[b * 1152 + f] = acc;
  }
}

// final LN over agg
__global__ __launch_bounds__(256) void k_lnm(const float* __restrict__ AG,
                                             const float* __restrict__ lg,
                                             const float* __restrict__ lb,
                                             float* __restrict__ AGN) {
  __shared__ float sb[4];
  int b = blockIdx.x;
  int tid = threadIdx.x;
  const float* xr = AG + b * 1152;
  float xl[5];
  int cnt = 0;
  float s = 0.f;
  for (int i = tid; i < 1152; i += 256) { xl[cnt] = xr[i]; s += xl[cnt]; ++cnt; }
  float tot = block_sum(s, sb);
  float mean = tot * (1.f / 1152.f);
  float q = 0.f;
  for (int k = 0; k < cnt; ++k) { float dd = xl[k] - mean; q += dd * dd; }
  float qt = block_sum(q, sb);
  float rs = rsqrtf(qt * (1.f / 1152.f) + 1e-5f);
  cnt = 0;
  for (int i = tid; i < 1152; i += 256) {
    AGN[b * 1152 + i] = (xl[cnt] - mean) * rs * lg[i] + lb[i];
    ++cnt;
  }
}

// g1 = gelu(AGN @ m_w1 + m_b1), 1024 outs per b
__global__ __launch_bounds__(256) void k_g1(const float* __restrict__ AGN,
                                            const float* __restrict__ w1,
                                            const float* __restrict__ b1,
                                            float* __restrict__ G1) {
  int b = blockIdx.y;
  int j = blockIdx.x * 256 + threadIdx.x;   // 1024
  __shared__ float av[1152];
  for (int i = threadIdx.x; i < 1152; i += 256) av[i] = AGN[b * 1152 + i];
  __syncthreads();
  float acc = b1[j];
  for (int i = 0; i < 1152; ++i) acc += av[i] * w1[(size_t)i * 1024 + j];
  G1[b * 1024 + j] = gelu_t(acc);
}

// out = G1 @ m_w2 + m_b2 -> f32 d_out
__global__ __launch_bounds__(256) void k_f3(const float* __restrict__ G1,
                                            const float* __restrict__ w2,
                                            const float* __restrict__ b2v,
                                            float* __restrict__ out) {
  int b = blockIdx.y;
  int o = blockIdx.x * 256 + threadIdx.x;   // 768
  __shared__ float gv[1024];
  for (int i = threadIdx.x; i < 1024; i += 256) gv[i] = G1[b * 1024 + i];
  __syncthreads();
  float acc = b2v[o];
  for (int i = 0; i < 1024; ++i) acc += gv[i] * w2[(size_t)i * 768 + o];
  out[b * 768 + o] = acc;
}

extern "C" void kernel_launch(void* const* d_in, const int* in_sizes, int n_in,
                              void* d_out, int out_size, void* d_ws,
                              size_t ws_size, hipStream_t stream) {
  (void)in_sizes; (void)n_in; (void)out_size; (void)ws_size;
  const float* x      = (const float*)d_in[0];
  const int*   perm   = (const int*)d_in[1];
  const float* sp_w1  = (const float*)d_in[2];
  const float* sp_b1  = (const float*)d_in[3];
  const float* sp_w2  = (const float*)d_in[4];
  const float* sp_b2  = (const float*)d_in[5];
  const float* ln_g   = (const float*)d_in[6];
  const float* ln_b   = (const float*)d_in[7];
  const float* W_in   = (const float*)d_in[8];
  const float* conv_w = (const float*)d_in[9];
  const float* conv_b = (const float*)d_in[10];
  const float* W_x    = (const float*)d_in[11];
  const float* W_dt   = (const float*)d_in[12];
  const float* b_dt   = (const float*)d_in[13];
  const float* A_log  = (const float*)d_in[14];
  const float* Dp     = (const float*)d_in[15];
  const float* W_out  = (const float*)d_in[16];
  const float* b_out  = (const float*)d_in[17];
  const float* fuse_w = (const float*)d_in[18];
  const float* fuse_b = (const float*)d_in[19];
  const float* band_emb = (const float*)d_in[20];
  const float* band_pw  = (const float*)d_in[21];
  const float* band_pb  = (const float*)d_in[22];
  const float* pos_w  = (const float*)d_in[23];
  const float* pos_b  = (const float*)d_in[24];
  const float* hemi_w = (const float*)d_in[25];
  const float* hemi_b = (const float*)d_in[26];
  const float* a_ln_g = (const float*)d_in[27];
  const float* a_ln_b = (const float*)d_in[28];
  const float* a_w1   = (const float*)d_in[29];
  const float* a_b1   = (const float*)d_in[30];
  const float* a_w2   = (const float*)d_in[31];
  const float* a_b2   = (const float*)d_in[32];
  const float* m_ln_g = (const float*)d_in[33];
  const float* m_ln_b = (const float*)d_in[34];
  const float* m_w1   = (const float*)d_in[35];
  const float* m_b1   = (const float*)d_in[36];
  const float* m_w2   = (const float*)d_in[37];
  const float* m_b2   = (const float*)d_in[38];

  char* ws = (char*)d_ws;
  size_t off = 0;
  auto alloc = [&](size_t bytes) -> char* {
    char* p = ws + off;
    off += (bytes + 255) & ~(size_t)255;
    return p;
  };
  // peak ~138 MiB
  float* H    = (float*)alloc((size_t)TOKn * 128 * 4);   // 25.2M
  u16*   F    = (u16*)  alloc((size_t)TOKn * 128 * 2);   // 12.6M
  u16*   XLN  = (u16*)  alloc((size_t)TOKn * 128 * 2);   // 12.6M
  u16*   XZ   = (u16*)  alloc((size_t)TOKn * 512 * 2);   // 50.3M
  u16*   XC   = (u16*)  alloc((size_t)TOKn * 256 * 2);   // 25.2M
  float* XDBL = (float*)alloc((size_t)TOKn * 40 * 4);    // 7.9M
  float* W2T  = (float*)alloc(16384 * 4);
  float* XF   = (float*)alloc(768 * 256 * 4);
  float* FE   = (float*)alloc(768 * 128 * 4);
  float* TO   = (float*)alloc(1152 * 128 * 4);
  float* T2v  = (float*)alloc(147456 * 4);
  float* FL   = (float*)alloc(147456 * 4);
  float* LO   = (float*)alloc(128 * 4);
  float* AG   = (float*)alloc(4 * 1152 * 4);
  float* AGN  = (float*)alloc(4 * 1152 * 4);
  float* G1v  = (float*)alloc(4 * 1024 * 4);

  // spectral front-end
  k_w2t<<<dim3(64), dim3(256), 0, stream>>>(sp_w2, W2T);
  k_spec1<<<dim3(TOKn), dim3(128), 0, stream>>>(x, sp_w1, sp_b1, F);

  auto mamba_round = [&](int blk) {
    k_ln<<<dim3(TOKn / 4), dim3(256), 0, stream>>>(
        H, ln_g + blk * 128, ln_b + blk * 128, XLN);
    k_gemm<1><<<dim3(8, TOKn / 64), dim3(256), 0, stream>>>(
        XLN, W_in + (size_t)blk * 65536, nullptr, 128, 512, 0, nullptr, XZ);
    k_conv<<<dim3(TOKn * 64 / 256), dim3(256), 0, stream>>>(
        XZ, conv_w + blk * 1024, conv_b + blk * 256, XC);
    k_gemm<2><<<dim3(1, TOKn / 64), dim3(256), 0, stream>>>(
        XC, W_x + (size_t)blk * 10240, nullptr, 256, 40, 0, XDBL, nullptr);
    k_scan<<<dim3(BCn), dim3(256), 0, stream>>>(
        XDBL, XC, XZ, W_dt + blk * 2048, b_dt + blk * 256,
        A_log + blk * 4096, Dp + blk * 256);
    k_gemm<3><<<dim3(2, TOKn / 64), dim3(256), 0, stream>>>(
        XC, W_out + (size_t)blk * 32768, b_out + blk * 128, 256, 128, 0,
        H, nullptr);
  };

  // forward chain (blocks 0,1)
  k_gemm<0><<<dim3(2, TOKn / 64), dim3(256), 0, stream>>>(
      F, W2T, sp_b2, 128, 128, 0, H, nullptr);
  mamba_round(0);
  mamba_round(1);
  k_gather<<<dim3(384), dim3(256), 0, stream>>>(H, XF, 0, 0);

  // backward chain (blocks 2,3) on time-reversed h
  k_gemm<0><<<dim3(2, TOKn / 64), dim3(256), 0, stream>>>(
      F, W2T, sp_b2, 128, 128, 1, H, nullptr);
  mamba_round(2);
  mamba_round(3);
  k_gather<<<dim3(384), dim3(256), 0, stream>>>(H, XF, 128, 1);

  // tail
  k_fuse<<<dim3(768), dim3(128), 0, stream>>>(XF, fuse_w, fuse_b, FE);
  k_band<<<dim3(1152), dim3(128), 0, stream>>>(FE, band_pw, band_pb, band_emb, TO);
  k_pos<<<dim3(576), dim3(256), 0, stream>>>(TO, pos_w, pos_b, T2v);
  k_hemi<<<dim3(1152), dim3(128), 0, stream>>>(T2v, perm, hemi_w, hemi_b, FL);
  k_attn<<<dim3(128), dim3(256), 0, stream>>>(FL, a_ln_g, a_ln_b, a_w1, a_b1,
                                              a_w2, a_b2, LO);
  k_smagg<<<dim3(4), dim3(256), 0, stream>>>(FL, LO, AG);
  k_lnm<<<dim3(4), dim3(256), 0, stream>>>(AG, m_ln_g, m_ln_b, AGN);
  k_g1<<<dim3(4, 4), dim3(256), 0, stream>>>(AGN, m_w1, m_b1, G1v);
  k_f3<<<dim3(3, 4), dim3(256), 0, stream>>>(G1v, m_w2, m_b2, (float*)d_out);
}

// Round 7
// 2173.826 us; speedup vs baseline: 1.3921x; 1.1886x over previous
//
#include <hip/hip_runtime.h>

// ---------------------------------------------------------------------------
// CSBrainAlign: spectral conv -> 4 mamba blocks (fwd chain then bwd chain,
// sequential) -> fuse@6 positions -> band/pos/hemi -> attn pool -> MLP.
// EXTERNAL dtype: float32 (per reference), int32 perm. Internal acts bf16,
// residual H fp32, fuse path fp32, output fp32.
// R6: scan remapped: lane = (d_local<<4)|n  -> per-lane scalar recurrence,
//     4-shfl n-reduction, dt precomputed per 64-step chunk, 16 blocks/bc
//     (2048 blocks). Critical chain/step = exp+fma (~20cyc) vs 2100 before.
// ---------------------------------------------------------------------------

typedef unsigned short u16;

#define TT    384      // sequence length N*P
#define BCn   128      // B*C
#define TOKn  49152    // BCn*TT (one chain)
#define CH2   64       // scan chunk (steps)
#define NCH2  (TT/CH2) // 6 chunks

__device__ __forceinline__ float b2f(u16 u) {
  return __uint_as_float(((unsigned)u) << 16);
}
__device__ __forceinline__ u16 f2b(float f) {
  unsigned u = __float_as_uint(f);
  u += 0x7fffu + ((u >> 16) & 1u);   // RNE
  return (u16)(u >> 16);
}
__device__ __forceinline__ float gelu_t(float x) {
  float u2 = 1.5957691216057308f * (x + 0.044715f * x * x * x);
  float e = __expf(u2);
  float th = 1.f - 2.f / (e + 1.f);
  return 0.5f * x * (1.f + th);
}
__device__ __forceinline__ float silu_f(float x) { return x / (1.f + __expf(-x)); }
__device__ __forceinline__ float softplus_f(float x) {
  return fmaxf(x, 0.f) + log1pf(__expf(-fabsf(x)));
}

__device__ __forceinline__ float block_sum(float v, float* sb) {
  #pragma unroll
  for (int m = 32; m; m >>= 1) v += __shfl_xor(v, m);
  int lane = threadIdx.x & 63, wid = threadIdx.x >> 6;
  if (lane == 0) sb[wid] = v;
  __syncthreads();
  float tot = sb[0] + sb[1] + sb[2] + sb[3];
  __syncthreads();
  return tot;
}

// ---------------------------------------------------------------------------
// Tiled GEMM: out[tok][n] = X[tok][0:K] @ W[0:K][n]
// X: internal bf16. W: external f32. 64x64 tile, 256 thr, 4x4 reg blocking.
// EPI: 0 spectral -> H f32 (+bias; rev!=0 stores time-reversed)
//      1 W_in     -> XZ bf16 (Nw=512)
//      2 W_x      -> XDBL f32 (Nw=40, masked)
//      3 W_out    -> H += acc + bias
// ---------------------------------------------------------------------------
template <int EPI>
__global__ __launch_bounds__(256) void k_gemm(
    const u16* __restrict__ X, const float* __restrict__ W,
    const float* __restrict__ bias, int K, int Nw, int rev,
    float* __restrict__ o0, u16* __restrict__ ob0) {
  __shared__ float Xs[64][68];   // [k][tok], padded
  __shared__ float Ws[64][64];   // [k][n]
  const int tid = threadIdx.x;
  const int tx = tid & 15, ty = tid >> 4;
  const int n0 = blockIdx.x * 64;
  const int tok0 = blockIdx.y * 64;
  float acc[4][4] = {};

  for (int k0 = 0; k0 < K; k0 += 64) {
    #pragma unroll
    for (int r = 0; r < 2; ++r) {
      int idx = tid + r * 256;
      int tokL = idx >> 3, kk = (idx & 7) * 8;
      const u16* p = X + (size_t)(tok0 + tokL) * K + k0 + kk;
      uint4 v = *reinterpret_cast<const uint4*>(p);
      Xs[kk + 0][tokL] = __uint_as_float((v.x & 0xffffu) << 16);
      Xs[kk + 1][tokL] = __uint_as_float(v.x & 0xffff0000u);
      Xs[kk + 2][tokL] = __uint_as_float((v.y & 0xffffu) << 16);
      Xs[kk + 3][tokL] = __uint_as_float(v.y & 0xffff0000u);
      Xs[kk + 4][tokL] = __uint_as_float((v.z & 0xffffu) << 16);
      Xs[kk + 5][tokL] = __uint_as_float(v.z & 0xffff0000u);
      Xs[kk + 6][tokL] = __uint_as_float((v.w & 0xffffu) << 16);
      Xs[kk + 7][tokL] = __uint_as_float(v.w & 0xffff0000u);
    }
    #pragma unroll
    for (int r = 0; r < 2; ++r) {
      int idx = tid + r * 256;
      int kkL = idx >> 3, nn = (idx & 7) * 8;
      int gk = k0 + kkL, gn = n0 + nn;
      if (gn + 8 <= Nw) {
        float4 v0 = *reinterpret_cast<const float4*>(W + (size_t)gk * Nw + gn);
        float4 v1 = *reinterpret_cast<const float4*>(W + (size_t)gk * Nw + gn + 4);
        *reinterpret_cast<float4*>(&Ws[kkL][nn]) = v0;
        *reinterpret_cast<float4*>(&Ws[kkL][nn + 4]) = v1;
      } else {
        #pragma unroll
        for (int j = 0; j < 8; ++j)
          Ws[kkL][nn + j] = (gn + j < Nw) ? W[(size_t)gk * Nw + gn + j] : 0.f;
      }
    }
    __syncthreads();
    #pragma unroll 8
    for (int kk = 0; kk < 64; ++kk) {
      float4 xv = *reinterpret_cast<const float4*>(&Xs[kk][ty * 4]);
      float4 wv = *reinterpret_cast<const float4*>(&Ws[kk][tx * 4]);
      float xa[4] = {xv.x, xv.y, xv.z, xv.w};
      float wa[4] = {wv.x, wv.y, wv.z, wv.w};
      #pragma unroll
      for (int ii = 0; ii < 4; ++ii)
        #pragma unroll
        for (int jj = 0; jj < 4; ++jj)
          acc[ii][jj] = fmaf(xa[ii], wa[jj], acc[ii][jj]);
    }
    __syncthreads();
  }

  #pragma unroll
  for (int ii = 0; ii < 4; ++ii) {
    int tok = tok0 + ty * 4 + ii;
    #pragma unroll
    for (int jj = 0; jj < 4; ++jj) {
      int n = n0 + tx * 4 + jj;
      float v = acc[ii][jj];
      if (EPI == 0) {
        v += bias[n];
        int bc = tok / TT, t = tok % TT;
        int tok2 = rev ? (bc * TT + (TT - 1 - t)) : tok;
        o0[(size_t)tok2 * Nw + n] = v;
      } else if (EPI == 1) {
        ob0[(size_t)tok * Nw + n] = f2b(v);
      } else if (EPI == 2) {
        if (n < Nw) o0[(size_t)tok * Nw + n] = v;
      } else if (EPI == 3) {
        v += bias[n];
        o0[(size_t)tok * Nw + n] += v;
      }
    }
  }
}

// transpose sp_w2 (o,c) -> (c,o) f32 so GEMM sees W[k][n] row-major
__global__ __launch_bounds__(256) void k_w2t(const float* __restrict__ w2,
                                             float* __restrict__ w2t) {
  int i = blockIdx.x * 256 + threadIdx.x;  // 16384
  int o = i >> 7, c = i & 127;
  w2t[c * 128 + o] = w2[o * 128 + c];
}

// spectral conv7 (pad 3) + bias + gelu -> F bf16 [token][c]
__global__ __launch_bounds__(128) void k_spec1(const float* __restrict__ x,
                                               const float* __restrict__ w1,
                                               const float* __restrict__ b1,
                                               u16* __restrict__ F) {
  int token = blockIdx.x;
  int c = threadIdx.x;
  int bc = token / TT, t = token % TT;
  const float* xr = x + (size_t)bc * TT;
  const float* wr = w1 + c * 7;
  float acc = b1[c];
  #pragma unroll
  for (int k = 0; k < 7; ++k) {
    int tt = t + k - 3;
    float xv = (tt >= 0 && tt < TT) ? xr[tt] : 0.f;
    acc += xv * wr[k];
  }
  F[(size_t)token * 128 + c] = f2b(gelu_t(acc));
}

// per-token LayerNorm over D=128: H f32 -> XLN bf16 (weights pre-offset)
__global__ __launch_bounds__(256) void k_ln(const float* __restrict__ H,
                                            const float* __restrict__ gg,
                                            const float* __restrict__ bb,
                                            u16* __restrict__ XLN) {
  int tid = threadIdx.x;
  int lane = tid & 63, wid = tid >> 6;
  int token = blockIdx.x * 4 + wid;
  const float* hr = H + (size_t)token * 128;
  float a = hr[lane], b = hr[lane + 64];
  float s = a + b;
  #pragma unroll
  for (int m = 32; m; m >>= 1) s += __shfl_xor(s, m);
  float mean = s * (1.f / 128.f);
  float d1 = a - mean, d2 = b - mean;
  float q = d1 * d1 + d2 * d2;
  #pragma unroll
  for (int m = 32; m; m >>= 1) q += __shfl_xor(q, m);
  float rs = rsqrtf(q * (1.f / 128.f) + 1e-5f);
  XLN[(size_t)token * 128 + lane] = f2b(d1 * rs * gg[lane] + bb[lane]);
  XLN[(size_t)token * 128 + lane + 64] =
      f2b(d2 * rs * gg[lane + 64] + bb[lane + 64]);
}

// causal depthwise conv (DC=4) + silu : XZ[:, :256] -> XC (4 chan/thread)
__global__ __launch_bounds__(256) void k_conv(const u16* __restrict__ XZ,
                                              const float* __restrict__ cw,
                                              const float* __restrict__ cb,
                                              u16* __restrict__ XC) {
  int idx = blockIdx.x * 256 + threadIdx.x;   // TOKn * 64
  int d4 = idx & 63;
  int tokg = idx >> 6;
  int t = tokg % TT;
  int dbase = d4 * 4;
  const float* cwp = cw + dbase * 4;
  float wv[4][4];
  #pragma unroll
  for (int j = 0; j < 4; ++j)
    #pragma unroll
    for (int k = 0; k < 4; ++k) wv[j][k] = cwp[j * 4 + k];
  float accv[4];
  #pragma unroll
  for (int j = 0; j < 4; ++j) accv[j] = cb[dbase + j];
  #pragma unroll
  for (int k = 0; k < 4; ++k) {
    int tt = t + k - 3;
    if (tt < 0) continue;
    ushort4 xv = *reinterpret_cast<const ushort4*>(
        &XZ[(size_t)(tokg + k - 3) * 512 + dbase]);
    u16 xa[4];
    *reinterpret_cast<ushort4*>(xa) = xv;
    #pragma unroll
    for (int j = 0; j < 4; ++j) accv[j] += b2f(xa[j]) * wv[j][k];
  }
  u16 oa[4];
  #pragma unroll
  for (int j = 0; j < 4; ++j) oa[j] = f2b(silu_f(accv[j]));
  *reinterpret_cast<ushort4*>(&XC[(size_t)tokg * 256 + dbase]) =
      *reinterpret_cast<ushort4*>(oa);
}

// ---------------------------------------------------------------------------
// selective scan v5: grid = 128 bc x 16 dq (2048 blocks), 256 threads.
// Thread owns ONE scalar recurrence: n = tid&15, d_local = tid>>4,
// d = dq*16+d_local. Per chunk (64 steps): prefetch next chunk -> regs,
// compute dt[t][d] vectorized, scan (per-step: 1 exp + 1 fma feedback,
// 4-shfl n-reduction), epilogue applies Dp/silu(z) + coalesced store.
// ---------------------------------------------------------------------------
__global__ __launch_bounds__(256) void k_scan(
    const float* __restrict__ XDBL, u16* __restrict__ XC,
    const u16* __restrict__ XZ, const float* __restrict__ Wdt,
    const float* __restrict__ bdt, const float* __restrict__ Alog,
    const float* __restrict__ Dpv) {
  __shared__ float xdl[CH2 * 40];   // raw xdbl chunk   (10 KB)
  __shared__ float dtl[CH2 * 16];   // dt[t][d_local]   (4 KB)
  __shared__ u16   xcl[CH2 * 16];   // xc[t][d_local]   (2 KB)
  __shared__ u16   zl [CH2 * 16];   // z[t][d_local]    (2 KB)
  __shared__ float ybuf[CH2 * 16];  // y[t][d_local]    (4 KB)
  const int tid = threadIdx.x;
  const int bx = blockIdx.x;
  const int bc = bx >> 4, dq = bx & 15;
  const int n = tid & 15;           // state index (scan phase)
  const int dl = tid >> 4;          // d_local (scan phase)
  const int dcol = tid & 15;        // d_local (dt/epilogue phases)

  const int d_scan = dq * 16 + dl;
  const float An = -__expf(Alog[d_scan * 16 + n]);
  float wdtr[8];
  #pragma unroll
  for (int j = 0; j < 8; ++j) wdtr[j] = Wdt[j * 256 + dq * 16 + dcol];
  const float bd = bdt[dq * 16 + dcol];
  const float dpar = Dpv[dq * 16 + dcol];

  const size_t base = (size_t)bc * TT;
  const float* xdg = XDBL + base * 40;
  const unsigned* xcu = (const unsigned*)XC;
  const unsigned* zu  = (const unsigned*)XZ;

  float sx[10];
  unsigned scx[2], sz[2];
  auto issue_loads = [&](int c) {
    const float* p = xdg + (size_t)c * CH2 * 40;
    #pragma unroll
    for (int k = 0; k < 10; ++k) sx[k] = p[tid + k * 256];
    #pragma unroll
    for (int k = 0; k < 2; ++k) {
      int v = tid + k * 256;           // 0..511 : t = v>>3, pr = v&7
      int t = v >> 3, pr = v & 7;
      size_t tok = base + (size_t)c * CH2 + t;
      scx[k] = xcu[tok * 128 + dq * 8 + pr];
      sz[k]  = zu[tok * 256 + 128 + dq * 8 + pr];
    }
  };
  auto write_lds = [&]() {
    #pragma unroll
    for (int k = 0; k < 10; ++k) xdl[tid + k * 256] = sx[k];
    #pragma unroll
    for (int k = 0; k < 2; ++k) {
      int v = tid + k * 256;
      ((unsigned*)xcl)[v] = scx[k];
      ((unsigned*)zl)[v] = sz[k];
    }
  };

  issue_loads(0);
  write_lds();
  __syncthreads();

  float hc = 0.f;
  for (int c = 0; c < NCH2; ++c) {
    if (c + 1 < NCH2) issue_loads(c + 1);
    // phase B: dt for this chunk (4 values per thread, fixed dcol)
    #pragma unroll
    for (int k = 0; k < 4; ++k) {
      int v = tid + k * 256;
      int t = v >> 4;
      float acc = bd;
      #pragma unroll
      for (int j = 0; j < 8; ++j) acc += xdl[t * 40 + j] * wdtr[j];
      dtl[v] = softplus_f(acc);
    }
    __syncthreads();
    // phase C: scan 64 steps
    #pragma unroll 4
    for (int t = 0; t < CH2; ++t) {
      float dtv = dtl[t * 16 + dl];
      float xcv = b2f(xcl[t * 16 + dl]);
      float e = __expf(An * dtv);
      float bb = dtv * xcv * xdl[t * 40 + 8 + n];
      hc = fmaf(hc, e, bb);
      float yv = hc * xdl[t * 40 + 24 + n];
      yv += __shfl_xor(yv, 1);
      yv += __shfl_xor(yv, 2);
      yv += __shfl_xor(yv, 4);
      yv += __shfl_xor(yv, 8);
      if (n == 0) ybuf[t * 16 + dl] = yv;
    }
    __syncthreads();
    // phase D: epilogue + store
    #pragma unroll
    for (int k = 0; k < 4; ++k) {
      int v = tid + k * 256;
      int t = v >> 4;
      float y = ybuf[v];
      float xcv = b2f(xcl[v]);
      float zz = b2f(zl[v]);
      y = (y + xcv * dpar) * silu_f(zz);
      XC[(base + (size_t)c * CH2 + t) * 256 + dq * 16 + dcol] = f2b(y);
    }
    __syncthreads();
    // phase E: commit staged regs for next chunk
    if (c + 1 < NCH2) {
      write_lds();
      __syncthreads();
    }
  }
}

// gather the 6 needed positions into XF[768][256] f32 (half=0 fwd,128 bwd)
__global__ __launch_bounds__(256) void k_gather(const float* __restrict__ H,
                                                float* __restrict__ XF,
                                                int half, int revpos) {
  int i = blockIdx.x * 256 + threadIdx.x;   // 768*128
  int col = i & 127, row = i >> 7;
  int bc = row / 6, u = row % 6;
  int tu = 63 + 64 * u;
  int t = revpos ? (TT - 1 - tu) : tu;
  XF[(size_t)row * 256 + half + col] = H[(size_t)(bc * TT + t) * 128 + col];
}

// fuse: FE[row][d] = XF[row][:] @ fuse_w + fuse_b   (768 rows, K=256)
__global__ __launch_bounds__(128) void k_fuse(const float* __restrict__ XF,
                                              const float* __restrict__ fw,
                                              const float* __restrict__ fb,
                                              float* __restrict__ FE) {
  int row = blockIdx.x;
  int d = threadIdx.x;
  __shared__ float rows[256];
  rows[d] = XF[(size_t)row * 256 + d];
  rows[128 + d] = XF[(size_t)row * 256 + 128 + d];
  __syncthreads();
  float acc = fb[d];
  for (int k = 0; k < 256; ++k) acc += rows[k] * fw[k * 128 + d];
  FE[(size_t)row * 128 + d] = acc;
}

// band projection + event reorder: TO[(bc*9+j)][d]
__global__ __launch_bounds__(128) void k_band(const float* __restrict__ FE,
                                              const float* __restrict__ pw,
                                              const float* __restrict__ pb,
                                              const float* __restrict__ pe,
                                              float* __restrict__ TO) {
  const int u_of[9] = {0, 1, 2, 2, 3, 4, 5, 5, 5};
  const int k_of[9] = {0, 0, 0, 1, 0, 0, 0, 1, 2};
  int bid = blockIdx.x;
  int bc = bid / 9, j = bid % 9;
  int u = u_of[j], kq = k_of[j];
  __shared__ float fs[128];
  int d = threadIdx.x;
  fs[d] = FE[(size_t)(bc * 6 + u) * 128 + d];
  __syncthreads();
  float acc = pb[kq * 128 + d] + pe[kq * 128 + d];
  const float* wp = pw + kq * 16384 + d;
  for (int c = 0; c < 128; ++c) acc += fs[c] * wp[c * 128];
  TO[(size_t)bid * 128 + d] = acc;
}

// depthwise 19x7 pos conv over (C=32, L=9) + residual -> T2 [b][c][l][d]
__global__ __launch_bounds__(256) void k_pos(const float* __restrict__ TO,
                                             const float* __restrict__ pw,
                                             const float* __restrict__ pb,
                                             float* __restrict__ T2) {
  int idx = blockIdx.x * 256 + threadIdx.x;   // 147456
  int d = idx & 127;
  int l = (idx >> 7) % 9;
  int c = (idx / 1152) & 31;
  int b = idx / 36864;
  float acc = 0.f;
  const float* wd = pw + d * 133;
  for (int i = 0; i < 19; ++i) {
    int ci = c + i - 9;
    if (ci < 0 || ci >= 32) continue;
    const float* trow = TO + (size_t)(b * 32 + ci) * 9 * 128 + d;
    #pragma unroll
    for (int jj = 0; jj < 7; ++jj) {
      int lj = l + jj - 3;
      if (lj < 0 || lj >= 9) continue;
      acc += trow[lj * 128] * wd[i * 7 + jj];
    }
  }
  T2[idx] = TO[idx] + acc + pb[d];
}

// hemisphere fusion: concat(own, permuted) @ hemi_w + hemi_b -> FL (flatf)
__global__ __launch_bounds__(128) void k_hemi(const float* __restrict__ T2,
                                              const int* __restrict__ perm,
                                              const float* __restrict__ hw,
                                              const float* __restrict__ hb,
                                              float* __restrict__ FL) {
  int bid = blockIdx.x;   // b*288 + c*9 + l
  int b = bid / 288;
  int c = (bid / 9) % 32;
  int l = bid % 9;
  int pc = perm[b * 32 + c];
  __shared__ float rows[256];
  int d = threadIdx.x;
  rows[d] = T2[((size_t)(b * 32 + c) * 9 + l) * 128 + d];
  rows[128 + d] = T2[((size_t)(b * 32 + pc) * 9 + l) * 128 + d];
  __syncthreads();
  float acc = hb[d];
  for (int k = 0; k < 256; ++k) acc += rows[k] * hw[k * 128 + d];
  FL[(size_t)(b * 32 + c) * 1152 + l * 128 + d] = acc;
}

// attention logits: LN(1152) -> @a_w1(200) -> gelu -> @a_w2 -> logit
__global__ __launch_bounds__(256) void k_attn(
    const float* __restrict__ FL, const float* __restrict__ lg,
    const float* __restrict__ lb, const float* __restrict__ w1,
    const float* __restrict__ b1, const float* __restrict__ w2,
    const float* __restrict__ ab2, float* __restrict__ LO) {
  __shared__ float xn[1152];
  __shared__ float sb[4];
  int row = blockIdx.x;
  int tid = threadIdx.x;
  const float* xr = FL + (size_t)row * 1152;
  float xl[5];
  int cnt = 0;
  float s = 0.f;
  for (int i = tid; i < 1152; i += 256) { xl[cnt] = xr[i]; s += xl[cnt]; ++cnt; }
  float tot = block_sum(s, sb);
  float mean = tot * (1.f / 1152.f);
  float q = 0.f;
  for (int k = 0; k < cnt; ++k) { float dd = xl[k] - mean; q += dd * dd; }
  float qt = block_sum(q, sb);
  float rs = rsqrtf(qt * (1.f / 1152.f) + 1e-5f);
  cnt = 0;
  for (int i = tid; i < 1152; i += 256) {
    xn[i] = (xl[cnt] - mean) * rs * lg[i] + lb[i];
    ++cnt;
  }
  __syncthreads();
  float g = 0.f;
  if (tid < 200) {
    float acc = b1[tid];
    for (int i = 0; i < 1152; ++i) acc += xn[i] * w1[i * 200 + tid];
    g = gelu_t(acc);
  }
  __syncthreads();
  if (tid < 200) xn[tid] = g;
  __syncthreads();
  float s2 = (tid < 200) ? xn[tid] * w2[tid] : 0.f;
  float t2 = block_sum(s2, sb);
  if (tid == 0) LO[row] = t2 + ab2[0];
}

// softmax over C=32 + weighted aggregation of flatf -> AG[b][1152]
__global__ __launch_bounds__(256) void k_smagg(const float* __restrict__ FL,
                                               const float* __restrict__ LO,
                                               float* __restrict__ AG) {
  int b = blockIdx.x;
  int tid = threadIdx.x;
  __shared__ float w[32];
  if (tid == 0) {
    float mx = -1e30f;
    for (int c = 0; c < 32; ++c) mx = fmaxf(mx, LO[b * 32 + c]);
    float sum = 0.f;
    for (int c = 0; c < 32; ++c) { float e = __expf(LO[b * 32 + c] - mx); w[c] = e; sum += e; }
    float inv = 1.f / sum;
    for (int c = 0; c < 32; ++c) w[c] *= inv;
  }
  __syncthreads();
  for (int f = tid; f < 1152; f += 256) {
    float acc = 0.f;
    for (int c = 0; c < 32; ++c) acc += FL[(size_t)(b * 32 + c) * 1152 + f] * w[c];
    AG[b * 1152 + f] = acc;
  }
}

// final LN over agg
__global__ __launch_bounds__(256) void k_lnm(const float* __restrict__ AG,
                                             const float* __restrict__ lg,
                                             const float* __restrict__ lb,
                                             float* __restrict__ AGN) {
  __shared__ float sb[4];
  int b = blockIdx.x;
  int tid = threadIdx.x;
  const float* xr = AG + b * 1152;
  float xl[5];
  int cnt = 0;
  float s = 0.f;
  for (int i = tid; i < 1152; i += 256) { xl[cnt] = xr[i]; s += xl[cnt]; ++cnt; }
  float tot = block_sum(s, sb);
  float mean = tot * (1.f / 1152.f);
  float q = 0.f;
  for (int k = 0; k < cnt; ++k) { float dd = xl[k] - mean; q += dd * dd; }
  float qt = block_sum(q, sb);
  float rs = rsqrtf(qt * (1.f / 1152.f) + 1e-5f);
  cnt = 0;
  for (int i = tid; i < 1152; i += 256) {
    AGN[b * 1152 + i] = (xl[cnt] - mean) * rs * lg[i] + lb[i];
    ++cnt;
  }
}

// g1 = gelu(AGN @ m_w1 + m_b1), 1024 outs per b
__global__ __launch_bounds__(256) void k_g1(const float* __restrict__ AGN,
                                            const float* __restrict__ w1,
                                            const float* __restrict__ b1,
                                            float* __restrict__ G1) {
  int b = blockIdx.y;
  int j = blockIdx.x * 256 + threadIdx.x;   // 1024
  __shared__ float av[1152];
  for (int i = threadIdx.x; i < 1152; i += 256) av[i] = AGN[b * 1152 + i];
  __syncthreads();
  float acc = b1[j];
  for (int i = 0; i < 1152; ++i) acc += av[i] * w1[(size_t)i * 1024 + j];
  G1[b * 1024 + j] = gelu_t(acc);
}

// out = G1 @ m_w2 + m_b2 -> f32 d_out
__global__ __launch_bounds__(256) void k_f3(const float* __restrict__ G1,
                                            const float* __restrict__ w2,
                                            const float* __restrict__ b2v,
                                            float* __restrict__ out) {
  int b = blockIdx.y;
  int o = blockIdx.x * 256 + threadIdx.x;   // 768
  __shared__ float gv[1024];
  for (int i = threadIdx.x; i < 1024; i += 256) gv[i] = G1[b * 1024 + i];
  __syncthreads();
  float acc = b2v[o];
  for (int i = 0; i < 1024; ++i) acc += gv[i] * w2[(size_t)i * 768 + o];
  out[b * 768 + o] = acc;
}

extern "C" void kernel_launch(void* const* d_in, const int* in_sizes, int n_in,
                              void* d_out, int out_size, void* d_ws,
                              size_t ws_size, hipStream_t stream) {
  (void)in_sizes; (void)n_in; (void)out_size; (void)ws_size;
  const float* x      = (const float*)d_in[0];
  const int*   perm   = (const int*)d_in[1];
  const float* sp_w1  = (const float*)d_in[2];
  const float* sp_b1  = (const float*)d_in[3];
  const float* sp_w2  = (const float*)d_in[4];
  const float* sp_b2  = (const float*)d_in[5];
  const float* ln_g   = (const float*)d_in[6];
  const float* ln_b   = (const float*)d_in[7];
  const float* W_in   = (const float*)d_in[8];
  const float* conv_w = (const float*)d_in[9];
  const float* conv_b = (const float*)d_in[10];
  const float* W_x    = (const float*)d_in[11];
  const float* W_dt   = (const float*)d_in[12];
  const float* b_dt   = (const float*)d_in[13];
  const float* A_log  = (const float*)d_in[14];
  const float* Dp     = (const float*)d_in[15];
  const float* W_out  = (const float*)d_in[16];
  const float* b_out  = (const float*)d_in[17];
  const float* fuse_w = (const float*)d_in[18];
  const float* fuse_b = (const float*)d_in[19];
  const float* band_emb = (const float*)d_in[20];
  const float* band_pw  = (const float*)d_in[21];
  const float* band_pb  = (const float*)d_in[22];
  const float* pos_w  = (const float*)d_in[23];
  const float* pos_b  = (const float*)d_in[24];
  const float* hemi_w = (const float*)d_in[25];
  const float* hemi_b = (const float*)d_in[26];
  const float* a_ln_g = (const float*)d_in[27];
  const float* a_ln_b = (const float*)d_in[28];
  const float* a_w1   = (const float*)d_in[29];
  const float* a_b1   = (const float*)d_in[30];
  const float* a_w2   = (const float*)d_in[31];
  const float* a_b2   = (const float*)d_in[32];
  const float* m_ln_g = (const float*)d_in[33];
  const float* m_ln_b = (const float*)d_in[34];
  const float* m_w1   = (const float*)d_in[35];
  const float* m_b1   = (const float*)d_in[36];
  const float* m_w2   = (const float*)d_in[37];
  const float* m_b2   = (const float*)d_in[38];

  char* ws = (char*)d_ws;
  size_t off = 0;
  auto alloc = [&](size_t bytes) -> char* {
    char* p = ws + off;
    off += (bytes + 255) & ~(size_t)255;
    return p;
  };
  // peak ~138 MiB
  float* H    = (float*)alloc((size_t)TOKn * 128 * 4);   // 25.2M
  u16*   F    = (u16*)  alloc((size_t)TOKn * 128 * 2);   // 12.6M
  u16*   XLN  = (u16*)  alloc((size_t)TOKn * 128 * 2);   // 12.6M
  u16*   XZ   = (u16*)  alloc((size_t)TOKn * 512 * 2);   // 50.3M
  u16*   XC   = (u16*)  alloc((size_t)TOKn * 256 * 2);   // 25.2M
  float* XDBL = (float*)alloc((size_t)TOKn * 40 * 4);    // 7.9M
  float* W2T  = (float*)alloc(16384 * 4);
  float* XF   = (float*)alloc(768 * 256 * 4);
  float* FE   = (float*)alloc(768 * 128 * 4);
  float* TO   = (float*)alloc(1152 * 128 * 4);
  float* T2v  = (float*)alloc(147456 * 4);
  float* FL   = (float*)alloc(147456 * 4);
  float* LO   = (float*)alloc(128 * 4);
  float* AG   = (float*)alloc(4 * 1152 * 4);
  float* AGN  = (float*)alloc(4 * 1152 * 4);
  float* G1v  = (float*)alloc(4 * 1024 * 4);

  // spectral front-end
  k_w2t<<<dim3(64), dim3(256), 0, stream>>>(sp_w2, W2T);
  k_spec1<<<dim3(TOKn), dim3(128), 0, stream>>>(x, sp_w1, sp_b1, F);

  auto mamba_round = [&](int blk) {
    k_ln<<<dim3(TOKn / 4), dim3(256), 0, stream>>>(
        H, ln_g + blk * 128, ln_b + blk * 128, XLN);
    k_gemm<1><<<dim3(8, TOKn / 64), dim3(256), 0, stream>>>(
        XLN, W_in + (size_t)blk * 65536, nullptr, 128, 512, 0, nullptr, XZ);
    k_conv<<<dim3(TOKn * 64 / 256), dim3(256), 0, stream>>>(
        XZ, conv_w + blk * 1024, conv_b + blk * 256, XC);
    k_gemm<2><<<dim3(1, TOKn / 64), dim3(256), 0, stream>>>(
        XC, W_x + (size_t)blk * 10240, nullptr, 256, 40, 0, XDBL, nullptr);
    k_scan<<<dim3(BCn * 16), dim3(256), 0, stream>>>(
        XDBL, XC, XZ, W_dt + blk * 2048, b_dt + blk * 256,
        A_log + blk * 4096, Dp + blk * 256);
    k_gemm<3><<<dim3(2, TOKn / 64), dim3(256), 0, stream>>>(
        XC, W_out + (size_t)blk * 32768, b_out + blk * 128, 256, 128, 0,
        H, nullptr);
  };

  // forward chain (blocks 0,1)
  k_gemm<0><<<dim3(2, TOKn / 64), dim3(256), 0, stream>>>(
      F, W2T, sp_b2, 128, 128, 0, H, nullptr);
  mamba_round(0);
  mamba_round(1);
  k_gather<<<dim3(384), dim3(256), 0, stream>>>(H, XF, 0, 0);

  // backward chain (blocks 2,3) on time-reversed h
  k_gemm<0><<<dim3(2, TOKn / 64), dim3(256), 0, stream>>>(
      F, W2T, sp_b2, 128, 128, 1, H, nullptr);
  mamba_round(2);
  mamba_round(3);
  k_gather<<<dim3(384), dim3(256), 0, stream>>>(H, XF, 128, 1);

  // tail
  k_fuse<<<dim3(768), dim3(128), 0, stream>>>(XF, fuse_w, fuse_b, FE);
  k_band<<<dim3(1152), dim3(128), 0, stream>>>(FE, band_pw, band_pb, band_emb, TO);
  k_pos<<<dim3(576), dim3(256), 0, stream>>>(TO, pos_w, pos_b, T2v);
  k_hemi<<<dim3(1152), dim3(128), 0, stream>>>(T2v, perm, hemi_w, hemi_b, FL);
  k_attn<<<dim3(128), dim3(256), 0, stream>>>(FL, a_ln_g, a_ln_b, a_w1, a_b1,
                                              a_w2, a_b2, LO);
  k_smagg<<<dim3(4), dim3(256), 0, stream>>>(FL, LO, AG);
  k_lnm<<<dim3(4), dim3(256), 0, stream>>>(AG, m_ln_g, m_ln_b, AGN);
  k_g1<<<dim3(4, 4), dim3(256), 0, stream>>>(AGN, m_w1, m_b1, G1v);
  k_f3<<<dim3(3, 4), dim3(256), 0, stream>>>(G1v, m_w2, m_b2, (float*)d_out);
}

// Round 8
// 1683.592 us; speedup vs baseline: 1.7975x; 1.2912x over previous
//
#include <hip/hip_runtime.h>

// ---------------------------------------------------------------------------
// CSBrainAlign: spectral conv -> 4 mamba blocks (fwd chain then bwd chain,
// sequential) -> fuse@6 positions -> band/pos/hemi -> attn pool -> MLP.
// EXTERNAL dtype: float32 (per reference), int32 perm. Internal acts bf16,
// residual H fp32, fuse path fp32, output fp32.
// R6: scan lane=(d,n) remap — 256us (was 343).
// R7: GEMM family -> MFMA bf16 (k_mm): 64x64 tile, full-K LDS stage (+8 pad),
//     4 waves x (2x2) mfma_f32_16x16x32_bf16 frags, weights pre-transposed
//     to bf16 [n][k] by prep kernels. A matrices already bf16 in memory.
// ---------------------------------------------------------------------------

typedef unsigned short u16;
using bf16x8 = __attribute__((ext_vector_type(8))) short;
using f32x4  = __attribute__((ext_vector_type(4))) float;

#define TT    384      // sequence length N*P
#define BCn   128      // B*C
#define TOKn  49152    // BCn*TT (one chain)
#define CH2   64       // scan chunk (steps)
#define NCH2  (TT/CH2) // 6 chunks

__device__ __forceinline__ float b2f(u16 u) {
  return __uint_as_float(((unsigned)u) << 16);
}
__device__ __forceinline__ u16 f2b(float f) {
  unsigned u = __float_as_uint(f);
  u += 0x7fffu + ((u >> 16) & 1u);   // RNE
  return (u16)(u >> 16);
}
__device__ __forceinline__ float gelu_t(float x) {
  float u2 = 1.5957691216057308f * (x + 0.044715f * x * x * x);
  float e = __expf(u2);
  float th = 1.f - 2.f / (e + 1.f);
  return 0.5f * x * (1.f + th);
}
__device__ __forceinline__ float silu_f(float x) { return x / (1.f + __expf(-x)); }
__device__ __forceinline__ float softplus_f(float x) {
  return fmaxf(x, 0.f) + log1pf(__expf(-fabsf(x)));
}

__device__ __forceinline__ float block_sum(float v, float* sb) {
  #pragma unroll
  for (int m = 32; m; m >>= 1) v += __shfl_xor(v, m);
  int lane = threadIdx.x & 63, wid = threadIdx.x >> 6;
  if (lane == 0) sb[wid] = v;
  __syncthreads();
  float tot = sb[0] + sb[1] + sb[2] + sb[3];
  __syncthreads();
  return tot;
}

// ---------------------------------------------------------------------------
// MFMA GEMM: out[tok][n] = X[tok][0:KT] @ W[0:KT][n],  X bf16, WT bf16 [n][k].
// 64x64 tile, 256 thr = 4 waves, each wave 32x32 via 2x2 16x16x32 frags.
// EPI: 0 spectral -> H f32 (+bias; rev!=0 time-reversed)
//      1 W_in     -> XZ bf16 (stride Nw=512)
//      2 W_x      -> XDBL f32 (stride 40, store n<40)
//      3 W_out    -> H += acc + bias
// ---------------------------------------------------------------------------
template <int EPI, int KT>
__global__ __launch_bounds__(256) void k_mm(
    const u16* __restrict__ X, const u16* __restrict__ WT,
    const float* __restrict__ bias, int Nw, int rev,
    float* __restrict__ o0, u16* __restrict__ ob0) {
  constexpr int AK = KT + 8;          // row pad: 16B-aligned, breaks pow2
  __shared__ u16 As[64 * AK];
  __shared__ u16 Bs[64 * AK];
  const int tid = threadIdx.x;
  const int n0 = blockIdx.x * 64;
  const int tok0 = blockIdx.y * 64;

  constexpr int VPR = KT / 8;          // uint4 per row
  constexpr int ITER = 64 * VPR / 256; // 4 (K=128) or 8 (K=256)
  #pragma unroll
  for (int j = 0; j < ITER; ++j) {
    int idx = tid + j * 256;
    int row = idx / VPR, vec = idx % VPR;
    *reinterpret_cast<uint4*>(&As[row * AK + vec * 8]) =
        *reinterpret_cast<const uint4*>(&X[(size_t)(tok0 + row) * KT + vec * 8]);
    *reinterpret_cast<uint4*>(&Bs[row * AK + vec * 8]) =
        *reinterpret_cast<const uint4*>(&WT[(size_t)(n0 + row) * KT + vec * 8]);
  }
  __syncthreads();

  const int w = tid >> 6, lane = tid & 63;
  const int wm = (w & 1) * 32, wn = (w >> 1) * 32;
  const int lrow = lane & 15, quad = lane >> 4;
  f32x4 acc[2][2] = {};
  #pragma unroll
  for (int ks = 0; ks < KT / 32; ++ks) {
    int koff = ks * 32 + quad * 8;
    bf16x8 a0 = *reinterpret_cast<const bf16x8*>(&As[(wm + lrow) * AK + koff]);
    bf16x8 a1 = *reinterpret_cast<const bf16x8*>(&As[(wm + 16 + lrow) * AK + koff]);
    bf16x8 b0 = *reinterpret_cast<const bf16x8*>(&Bs[(wn + lrow) * AK + koff]);
    bf16x8 b1 = *reinterpret_cast<const bf16x8*>(&Bs[(wn + 16 + lrow) * AK + koff]);
    acc[0][0] = __builtin_amdgcn_mfma_f32_16x16x32_bf16(a0, b0, acc[0][0], 0, 0, 0);
    acc[0][1] = __builtin_amdgcn_mfma_f32_16x16x32_bf16(a0, b1, acc[0][1], 0, 0, 0);
    acc[1][0] = __builtin_amdgcn_mfma_f32_16x16x32_bf16(a1, b0, acc[1][0], 0, 0, 0);
    acc[1][1] = __builtin_amdgcn_mfma_f32_16x16x32_bf16(a1, b1, acc[1][1], 0, 0, 0);
  }

  #pragma unroll
  for (int mi = 0; mi < 2; ++mi)
    #pragma unroll
    for (int ni = 0; ni < 2; ++ni)
      #pragma unroll
      for (int r = 0; r < 4; ++r) {
        int tok = tok0 + wm + mi * 16 + quad * 4 + r;
        int n = n0 + wn + ni * 16 + lrow;
        float v = acc[mi][ni][r];
        if (EPI == 0) {
          v += bias[n];
          int bc = tok / TT, t = tok % TT;
          int tok2 = rev ? (bc * TT + (TT - 1 - t)) : tok;
          o0[(size_t)tok2 * 128 + n] = v;
        } else if (EPI == 1) {
          ob0[(size_t)tok * 512 + n] = f2b(v);
        } else if (EPI == 2) {
          if (n < 40) o0[(size_t)tok * 40 + n] = v;
        } else if (EPI == 3) {
          v += bias[n];
          o0[(size_t)tok * 128 + n] += v;
        }
      }
  (void)Nw;
}

// ---- weight prep: f32 -> bf16, transposed to [n][k] ----
__global__ __launch_bounds__(256) void k_tin(const float* __restrict__ W,
                                             u16* __restrict__ WT) {
  int i = blockIdx.x * 256 + threadIdx.x;   // 4*512*128
  int blk = i >> 16, r = i & 65535;
  int n = r >> 7, k = r & 127;
  WT[i] = f2b(W[blk * 65536 + k * 512 + n]);
}
__global__ __launch_bounds__(256) void k_tout(const float* __restrict__ W,
                                              u16* __restrict__ WT) {
  int i = blockIdx.x * 256 + threadIdx.x;   // 4*128*256
  int blk = i >> 15, r = i & 32767;
  int n = r >> 8, k = r & 255;
  WT[i] = f2b(W[blk * 32768 + k * 128 + n]);
}
__global__ __launch_bounds__(256) void k_tx(const float* __restrict__ W,
                                            u16* __restrict__ WT) {
  int i = blockIdx.x * 256 + threadIdx.x;   // 4*64*256
  int blk = i >> 14, r = i & 16383;
  int n = r >> 8, k = r & 255;
  WT[i] = (n < 40) ? f2b(W[blk * 10240 + k * 40 + n]) : 0;
}
__global__ __launch_bounds__(256) void k_tsp(const float* __restrict__ W,
                                             u16* __restrict__ WT) {
  int i = blockIdx.x * 256 + threadIdx.x;   // 128*128 ([o][c] directly)
  WT[i] = f2b(W[i]);
}

// spectral conv7 (pad 3) + bias + gelu -> F bf16 [token][c]
__global__ __launch_bounds__(128) void k_spec1(const float* __restrict__ x,
                                               const float* __restrict__ w1,
                                               const float* __restrict__ b1,
                                               u16* __restrict__ F) {
  int token = blockIdx.x;
  int c = threadIdx.x;
  int bc = token / TT, t = token % TT;
  const float* xr = x + (size_t)bc * TT;
  const float* wr = w1 + c * 7;
  float acc = b1[c];
  #pragma unroll
  for (int k = 0; k < 7; ++k) {
    int tt = t + k - 3;
    float xv = (tt >= 0 && tt < TT) ? xr[tt] : 0.f;
    acc += xv * wr[k];
  }
  F[(size_t)token * 128 + c] = f2b(gelu_t(acc));
}

// per-token LayerNorm over D=128: H f32 -> XLN bf16 (weights pre-offset)
__global__ __launch_bounds__(256) void k_ln(const float* __restrict__ H,
                                            const float* __restrict__ gg,
                                            const float* __restrict__ bb,
                                            u16* __restrict__ XLN) {
  int tid = threadIdx.x;
  int lane = tid & 63, wid = tid >> 6;
  int token = blockIdx.x * 4 + wid;
  const float* hr = H + (size_t)token * 128;
  float a = hr[lane], b = hr[lane + 64];
  float s = a + b;
  #pragma unroll
  for (int m = 32; m; m >>= 1) s += __shfl_xor(s, m);
  float mean = s * (1.f / 128.f);
  float d1 = a - mean, d2 = b - mean;
  float q = d1 * d1 + d2 * d2;
  #pragma unroll
  for (int m = 32; m; m >>= 1) q += __shfl_xor(q, m);
  float rs = rsqrtf(q * (1.f / 128.f) + 1e-5f);
  XLN[(size_t)token * 128 + lane] = f2b(d1 * rs * gg[lane] + bb[lane]);
  XLN[(size_t)token * 128 + lane + 64] =
      f2b(d2 * rs * gg[lane + 64] + bb[lane + 64]);
}

// causal depthwise conv (DC=4) + silu : XZ[:, :256] -> XC (4 chan/thread)
__global__ __launch_bounds__(256) void k_conv(const u16* __restrict__ XZ,
                                              const float* __restrict__ cw,
                                              const float* __restrict__ cb,
                                              u16* __restrict__ XC) {
  int idx = blockIdx.x * 256 + threadIdx.x;   // TOKn * 64
  int d4 = idx & 63;
  int tokg = idx >> 6;
  int t = tokg % TT;
  int dbase = d4 * 4;
  const float* cwp = cw + dbase * 4;
  float wv[4][4];
  #pragma unroll
  for (int j = 0; j < 4; ++j)
    #pragma unroll
    for (int k = 0; k < 4; ++k) wv[j][k] = cwp[j * 4 + k];
  float accv[4];
  #pragma unroll
  for (int j = 0; j < 4; ++j) accv[j] = cb[dbase + j];
  #pragma unroll
  for (int k = 0; k < 4; ++k) {
    int tt = t + k - 3;
    if (tt < 0) continue;
    ushort4 xv = *reinterpret_cast<const ushort4*>(
        &XZ[(size_t)(tokg + k - 3) * 512 + dbase]);
    u16 xa[4];
    *reinterpret_cast<ushort4*>(xa) = xv;
    #pragma unroll
    for (int j = 0; j < 4; ++j) accv[j] += b2f(xa[j]) * wv[j][k];
  }
  u16 oa[4];
  #pragma unroll
  for (int j = 0; j < 4; ++j) oa[j] = f2b(silu_f(accv[j]));
  *reinterpret_cast<ushort4*>(&XC[(size_t)tokg * 256 + dbase]) =
      *reinterpret_cast<ushort4*>(oa);
}

// selective scan v5 (unchanged from R6): 128 bc x 16 dq blocks, 256 thr,
// thread owns one (d,n) scalar recurrence; dt precomputed per 64-step chunk.
__global__ __launch_bounds__(256) void k_scan(
    const float* __restrict__ XDBL, u16* __restrict__ XC,
    const u16* __restrict__ XZ, const float* __restrict__ Wdt,
    const float* __restrict__ bdt, const float* __restrict__ Alog,
    const float* __restrict__ Dpv) {
  __shared__ float xdl[CH2 * 40];
  __shared__ float dtl[CH2 * 16];
  __shared__ u16   xcl[CH2 * 16];
  __shared__ u16   zl [CH2 * 16];
  __shared__ float ybuf[CH2 * 16];
  const int tid = threadIdx.x;
  const int bx = blockIdx.x;
  const int bc = bx >> 4, dq = bx & 15;
  const int n = tid & 15;
  const int dl = tid >> 4;
  const int dcol = tid & 15;

  const int d_scan = dq * 16 + dl;
  const float An = -__expf(Alog[d_scan * 16 + n]);
  float wdtr[8];
  #pragma unroll
  for (int j = 0; j < 8; ++j) wdtr[j] = Wdt[j * 256 + dq * 16 + dcol];
  const float bd = bdt[dq * 16 + dcol];
  const float dpar = Dpv[dq * 16 + dcol];

  const size_t base = (size_t)bc * TT;
  const float* xdg = XDBL + base * 40;
  const unsigned* xcu = (const unsigned*)XC;
  const unsigned* zu  = (const unsigned*)XZ;

  float sx[10];
  unsigned scx[2], sz[2];
  auto issue_loads = [&](int c) {
    const float* p = xdg + (size_t)c * CH2 * 40;
    #pragma unroll
    for (int k = 0; k < 10; ++k) sx[k] = p[tid + k * 256];
    #pragma unroll
    for (int k = 0; k < 2; ++k) {
      int v = tid + k * 256;
      int t = v >> 3, pr = v & 7;
      size_t tok = base + (size_t)c * CH2 + t;
      scx[k] = xcu[tok * 128 + dq * 8 + pr];
      sz[k]  = zu[tok * 256 + 128 + dq * 8 + pr];
    }
  };
  auto write_lds = [&]() {
    #pragma unroll
    for (int k = 0; k < 10; ++k) xdl[tid + k * 256] = sx[k];
    #pragma unroll
    for (int k = 0; k < 2; ++k) {
      int v = tid + k * 256;
      ((unsigned*)xcl)[v] = scx[k];
      ((unsigned*)zl)[v] = sz[k];
    }
  };

  issue_loads(0);
  write_lds();
  __syncthreads();

  float hc = 0.f;
  for (int c = 0; c < NCH2; ++c) {
    if (c + 1 < NCH2) issue_loads(c + 1);
    #pragma unroll
    for (int k = 0; k < 4; ++k) {
      int v = tid + k * 256;
      int t = v >> 4;
      float acc = bd;
      #pragma unroll
      for (int j = 0; j < 8; ++j) acc += xdl[t * 40 + j] * wdtr[j];
      dtl[v] = softplus_f(acc);
    }
    __syncthreads();
    #pragma unroll 4
    for (int t = 0; t < CH2; ++t) {
      float dtv = dtl[t * 16 + dl];
      float xcv = b2f(xcl[t * 16 + dl]);
      float e = __expf(An * dtv);
      float bb = dtv * xcv * xdl[t * 40 + 8 + n];
      hc = fmaf(hc, e, bb);
      float yv = hc * xdl[t * 40 + 24 + n];
      yv += __shfl_xor(yv, 1);
      yv += __shfl_xor(yv, 2);
      yv += __shfl_xor(yv, 4);
      yv += __shfl_xor(yv, 8);
      if (n == 0) ybuf[t * 16 + dl] = yv;
    }
    __syncthreads();
    #pragma unroll
    for (int k = 0; k < 4; ++k) {
      int v = tid + k * 256;
      int t = v >> 4;
      float y = ybuf[v];
      float xcv = b2f(xcl[v]);
      float zz = b2f(zl[v]);
      y = (y + xcv * dpar) * silu_f(zz);
      XC[(base + (size_t)c * CH2 + t) * 256 + dq * 16 + dcol] = f2b(y);
    }
    __syncthreads();
    if (c + 1 < NCH2) {
      write_lds();
      __syncthreads();
    }
  }
}

// gather the 6 needed positions into XF[768][256] f32 (half=0 fwd,128 bwd)
__global__ __launch_bounds__(256) void k_gather(const float* __restrict__ H,
                                                float* __restrict__ XF,
                                                int half, int revpos) {
  int i = blockIdx.x * 256 + threadIdx.x;   // 768*128
  int col = i & 127, row = i >> 7;
  int bc = row / 6, u = row % 6;
  int tu = 63 + 64 * u;
  int t = revpos ? (TT - 1 - tu) : tu;
  XF[(size_t)row * 256 + half + col] = H[(size_t)(bc * TT + t) * 128 + col];
}

// fuse: FE[row][d] = XF[row][:] @ fuse_w + fuse_b   (768 rows, K=256)
__global__ __launch_bounds__(128) void k_fuse(const float* __restrict__ XF,
                                              const float* __restrict__ fw,
                                              const float* __restrict__ fb,
                                              float* __restrict__ FE) {
  int row = blockIdx.x;
  int d = threadIdx.x;
  __shared__ float rows[256];
  rows[d] = XF[(size_t)row * 256 + d];
  rows[128 + d] = XF[(size_t)row * 256 + 128 + d];
  __syncthreads();
  float acc = fb[d];
  for (int k = 0; k < 256; ++k) acc += rows[k] * fw[k * 128 + d];
  FE[(size_t)row * 128 + d] = acc;
}

// band projection + event reorder: TO[(bc*9+j)][d]
__global__ __launch_bounds__(128) void k_band(const float* __restrict__ FE,
                                              const float* __restrict__ pw,
                                              const float* __restrict__ pb,
                                              const float* __restrict__ pe,
                                              float* __restrict__ TO) {
  const int u_of[9] = {0, 1, 2, 2, 3, 4, 5, 5, 5};
  const int k_of[9] = {0, 0, 0, 1, 0, 0, 0, 1, 2};
  int bid = blockIdx.x;
  int bc = bid / 9, j = bid % 9;
  int u = u_of[j], kq = k_of[j];
  __shared__ float fs[128];
  int d = threadIdx.x;
  fs[d] = FE[(size_t)(bc * 6 + u) * 128 + d];
  __syncthreads();
  float acc = pb[kq * 128 + d] + pe[kq * 128 + d];
  const float* wp = pw + kq * 16384 + d;
  for (int c = 0; c < 128; ++c) acc += fs[c] * wp[c * 128];
  TO[(size_t)bid * 128 + d] = acc;
}

// depthwise 19x7 pos conv over (C=32, L=9) + residual -> T2 [b][c][l][d]
__global__ __launch_bounds__(256) void k_pos(const float* __restrict__ TO,
                                             const float* __restrict__ pw,
                                             const float* __restrict__ pb,
                                             float* __restrict__ T2) {
  int idx = blockIdx.x * 256 + threadIdx.x;   // 147456
  int d = idx & 127;
  int l = (idx >> 7) % 9;
  int c = (idx / 1152) & 31;
  int b = idx / 36864;
  float acc = 0.f;
  const float* wd = pw + d * 133;
  for (int i = 0; i < 19; ++i) {
    int ci = c + i - 9;
    if (ci < 0 || ci >= 32) continue;
    const float* trow = TO + (size_t)(b * 32 + ci) * 9 * 128 + d;
    #pragma unroll
    for (int jj = 0; jj < 7; ++jj) {
      int lj = l + jj - 3;
      if (lj < 0 || lj >= 9) continue;
      acc += trow[lj * 128] * wd[i * 7 + jj];
    }
  }
  T2[idx] = TO[idx] + acc + pb[d];
}

// hemisphere fusion: concat(own, permuted) @ hemi_w + hemi_b -> FL (flatf)
__global__ __launch_bounds__(128) void k_hemi(const float* __restrict__ T2,
                                              const int* __restrict__ perm,
                                              const float* __restrict__ hw,
                                              const float* __restrict__ hb,
                                              float* __restrict__ FL) {
  int bid = blockIdx.x;   // b*288 + c*9 + l
  int b = bid / 288;
  int c = (bid / 9) % 32;
  int l = bid % 9;
  int pc = perm[b * 32 + c];
  __shared__ float rows[256];
  int d = threadIdx.x;
  rows[d] = T2[((size_t)(b * 32 + c) * 9 + l) * 128 + d];
  rows[128 + d] = T2[((size_t)(b * 32 + pc) * 9 + l) * 128 + d];
  __syncthreads();
  float acc = hb[d];
  for (int k = 0; k < 256; ++k) acc += rows[k] * hw[k * 128 + d];
  FL[(size_t)(b * 32 + c) * 1152 + l * 128 + d] = acc;
}

// attention logits: LN(1152) -> @a_w1(200) -> gelu -> @a_w2 -> logit
__global__ __launch_bounds__(256) void k_attn(
    const float* __restrict__ FL, const float* __restrict__ lg,
    const float* __restrict__ lb, const float* __restrict__ w1,
    const float* __restrict__ b1, const float* __restrict__ w2,
    const float* __restrict__ ab2, float* __restrict__ LO) {
  __shared__ float xn[1152];
  __shared__ float sb[4];
  int row = blockIdx.x;
  int tid = threadIdx.x;
  const float* xr = FL + (size_t)row * 1152;
  float xl[5];
  int cnt = 0;
  float s = 0.f;
  for (int i = tid; i < 1152; i += 256) { xl[cnt] = xr[i]; s += xl[cnt]; ++cnt; }
  float tot = block_sum(s, sb);
  float mean = tot * (1.f / 1152.f);
  float q = 0.f;
  for (int k = 0; k < cnt; ++k) { float dd = xl[k] - mean; q += dd * dd; }
  float qt = block_sum(q, sb);
  float rs = rsqrtf(qt * (1.f / 1152.f) + 1e-5f);
  cnt = 0;
  for (int i = tid; i < 1152; i += 256) {
    xn[i] = (xl[cnt] - mean) * rs * lg[i] + lb[i];
    ++cnt;
  }
  __syncthreads();
  float g = 0.f;
  if (tid < 200) {
    float acc = b1[tid];
    for (int i = 0; i < 1152; ++i) acc += xn[i] * w1[i * 200 + tid];
    g = gelu_t(acc);
  }
  __syncthreads();
  if (tid < 200) xn[tid] = g;
  __syncthreads();
  float s2 = (tid < 200) ? xn[tid] * w2[tid] : 0.f;
  float t2 = block_sum(s2, sb);
  if (tid == 0) LO[row] = t2 + ab2[0];
}

// softmax over C=32 + weighted aggregation of flatf -> AG[b][1152]
__global__ __launch_bounds__(256) void k_smagg(const float* __restrict__ FL,
                                               const float* __restrict__ LO,
                                               float* __restrict__ AG) {
  int b = blockIdx.x;
  int tid = threadIdx.x;
  __shared__ float w[32];
  if (tid == 0) {
    float mx = -1e30f;
    for (int c = 0; c < 32; ++c) mx = fmaxf(mx, LO[b * 32 + c]);
    float sum = 0.f;
    for (int c = 0; c < 32; ++c) { float e = __expf(LO[b * 32 + c] - mx); w[c] = e; sum += e; }
    float inv = 1.f / sum;
    for (int c = 0; c < 32; ++c) w[c] *= inv;
  }
  __syncthreads();
  for (int f = tid; f < 1152; f += 256) {
    float acc = 0.f;
    for (int c = 0; c < 32; ++c) acc += FL[(size_t)(b * 32 + c) * 1152 + f] * w[c];
    AG[b * 1152 + f] = acc;
  }
}

// final LN over agg
__global__ __launch_bounds__(256) void k_lnm(const float* __restrict__ AG,
                                             const float* __restrict__ lg,
                                             const float* __restrict__ lb,
                                             float* __restrict__ AGN) {
  __shared__ float sb[4];
  int b = blockIdx.x;
  int tid = threadIdx.x;
  const float* xr = AG + b * 1152;
  float xl[5];
  int cnt = 0;
  float s = 0.f;
  for (int i = tid; i < 1152; i += 256) { xl[cnt] = xr[i]; s += xl[cnt]; ++cnt; }
  float tot = block_sum(s, sb);
  float mean = tot * (1.f / 1152.f);
  float q = 0.f;
  for (int k = 0; k < cnt; ++k) { float dd = xl[k] - mean; q += dd * dd; }
  float qt = block_sum(q, sb);
  float rs = rsqrtf(qt * (1.f / 1152.f) + 1e-5f);
  cnt = 0;
  for (int i = tid; i < 1152; i += 256) {
    AGN[b * 1152 + i] = (xl[cnt] - mean) * rs * lg[i] + lb[i];
    ++cnt;
  }
}

// g1 = gelu(AGN @ m_w1 + m_b1), 1024 outs per b
__global__ __launch_bounds__(256) void k_g1(const float* __restrict__ AGN,
                                            const float* __restrict__ w1,
                                            const float* __restrict__ b1,
                                            float* __restrict__ G1) {
  int b = blockIdx.y;
  int j = blockIdx.x * 256 + threadIdx.x;   // 1024
  __shared__ float av[1152];
  for (int i = threadIdx.x; i < 1152; i += 256) av[i] = AGN[b * 1152 + i];
  __syncthreads();
  float acc = b1[j];
  for (int i = 0; i < 1152; ++i) acc += av[i] * w1[(size_t)i * 1024 + j];
  G1[b * 1024 + j] = gelu_t(acc);
}

// out = G1 @ m_w2 + m_b2 -> f32 d_out
__global__ __launch_bounds__(256) void k_f3(const float* __restrict__ G1,
                                            const float* __restrict__ w2,
                                            const float* __restrict__ b2v,
                                            float* __restrict__ out) {
  int b = blockIdx.y;
  int o = blockIdx.x * 256 + threadIdx.x;   // 768
  __shared__ float gv[1024];
  for (int i = threadIdx.x; i < 1024; i += 256) gv[i] = G1[b * 1024 + i];
  __syncthreads();
  float acc = b2v[o];
  for (int i = 0; i < 1024; ++i) acc += gv[i] * w2[(size_t)i * 768 + o];
  out[b * 768 + o] = acc;
}

extern "C" void kernel_launch(void* const* d_in, const int* in_sizes, int n_in,
                              void* d_out, int out_size, void* d_ws,
                              size_t ws_size, hipStream_t stream) {
  (void)in_sizes; (void)n_in; (void)out_size; (void)ws_size;
  const float* x      = (const float*)d_in[0];
  const int*   perm   = (const int*)d_in[1];
  const float* sp_w1  = (const float*)d_in[2];
  const float* sp_b1  = (const float*)d_in[3];
  const float* sp_w2  = (const float*)d_in[4];
  const float* sp_b2  = (const float*)d_in[5];
  const float* ln_g   = (const float*)d_in[6];
  const float* ln_b   = (const float*)d_in[7];
  const float* W_in   = (const float*)d_in[8];
  const float* conv_w = (const float*)d_in[9];
  const float* conv_b = (const float*)d_in[10];
  const float* W_x    = (const float*)d_in[11];
  const float* W_dt   = (const float*)d_in[12];
  const float* b_dt   = (const float*)d_in[13];
  const float* A_log  = (const float*)d_in[14];
  const float* Dp     = (const float*)d_in[15];
  const float* W_out  = (const float*)d_in[16];
  const float* b_out  = (const float*)d_in[17];
  const float* fuse_w = (const float*)d_in[18];
  const float* fuse_b = (const float*)d_in[19];
  const float* band_emb = (const float*)d_in[20];
  const float* band_pw  = (const float*)d_in[21];
  const float* band_pb  = (const float*)d_in[22];
  const float* pos_w  = (const float*)d_in[23];
  const float* pos_b  = (const float*)d_in[24];
  const float* hemi_w = (const float*)d_in[25];
  const float* hemi_b = (const float*)d_in[26];
  const float* a_ln_g = (const float*)d_in[27];
  const float* a_ln_b = (const float*)d_in[28];
  const float* a_w1   = (const float*)d_in[29];
  const float* a_b1   = (const float*)d_in[30];
  const float* a_w2   = (const float*)d_in[31];
  const float* a_b2   = (const float*)d_in[32];
  const float* m_ln_g = (const float*)d_in[33];
  const float* m_ln_b = (const float*)d_in[34];
  const float* m_w1   = (const float*)d_in[35];
  const float* m_b1   = (const float*)d_in[36];
  const float* m_w2   = (const float*)d_in[37];
  const float* m_b2   = (const float*)d_in[38];

  char* ws = (char*)d_ws;
  size_t off = 0;
  auto alloc = [&](size_t bytes) -> char* {
    char* p = ws + off;
    off += (bytes + 255) & ~(size_t)255;
    return p;
  };
  // peak ~139 MiB
  float* H    = (float*)alloc((size_t)TOKn * 128 * 4);   // 25.2M
  u16*   F    = (u16*)  alloc((size_t)TOKn * 128 * 2);   // 12.6M
  u16*   XLN  = (u16*)  alloc((size_t)TOKn * 128 * 2);   // 12.6M
  u16*   XZ   = (u16*)  alloc((size_t)TOKn * 512 * 2);   // 50.3M
  u16*   XC   = (u16*)  alloc((size_t)TOKn * 256 * 2);   // 25.2M
  float* XDBL = (float*)alloc((size_t)TOKn * 40 * 4);    // 7.9M
  u16*   WTin = (u16*)alloc(4 * 512 * 128 * 2);
  u16*   WTout= (u16*)alloc(4 * 128 * 256 * 2);
  u16*   WTx  = (u16*)alloc(4 * 64 * 256 * 2);
  u16*   WTsp = (u16*)alloc(128 * 128 * 2);
  float* XF   = (float*)alloc(768 * 256 * 4);
  float* FE   = (float*)alloc(768 * 128 * 4);
  float* TO   = (float*)alloc(1152 * 128 * 4);
  float* T2v  = (float*)alloc(147456 * 4);
  float* FL   = (float*)alloc(147456 * 4);
  float* LO   = (float*)alloc(128 * 4);
  float* AG   = (float*)alloc(4 * 1152 * 4);
  float* AGN  = (float*)alloc(4 * 1152 * 4);
  float* G1v  = (float*)alloc(4 * 1024 * 4);

  // weight prep (bf16, [n][k])
  k_tin <<<dim3(1024), dim3(256), 0, stream>>>(W_in, WTin);
  k_tout<<<dim3(512),  dim3(256), 0, stream>>>(W_out, WTout);
  k_tx  <<<dim3(256),  dim3(256), 0, stream>>>(W_x, WTx);
  k_tsp <<<dim3(64),   dim3(256), 0, stream>>>(sp_w2, WTsp);

  // spectral front-end
  k_spec1<<<dim3(TOKn), dim3(128), 0, stream>>>(x, sp_w1, sp_b1, F);

  auto mamba_round = [&](int blk) {
    k_ln<<<dim3(TOKn / 4), dim3(256), 0, stream>>>(
        H, ln_g + blk * 128, ln_b + blk * 128, XLN);
    k_mm<1, 128><<<dim3(8, TOKn / 64), dim3(256), 0, stream>>>(
        XLN, WTin + (size_t)blk * 65536, nullptr, 512, 0, nullptr, XZ);
    k_conv<<<dim3(TOKn * 64 / 256), dim3(256), 0, stream>>>(
        XZ, conv_w + blk * 1024, conv_b + blk * 256, XC);
    k_mm<2, 256><<<dim3(1, TOKn / 64), dim3(256), 0, stream>>>(
        XC, WTx + (size_t)blk * 16384, nullptr, 40, 0, XDBL, nullptr);
    k_scan<<<dim3(BCn * 16), dim3(256), 0, stream>>>(
        XDBL, XC, XZ, W_dt + blk * 2048, b_dt + blk * 256,
        A_log + blk * 4096, Dp + blk * 256);
    k_mm<3, 256><<<dim3(2, TOKn / 64), dim3(256), 0, stream>>>(
        XC, WTout + (size_t)blk * 32768, b_out + blk * 128, 128, 0,
        H, nullptr);
  };

  // forward chain (blocks 0,1)
  k_mm<0, 128><<<dim3(2, TOKn / 64), dim3(256), 0, stream>>>(
      F, WTsp, sp_b2, 128, 0, H, nullptr);
  mamba_round(0);
  mamba_round(1);
  k_gather<<<dim3(384), dim3(256), 0, stream>>>(H, XF, 0, 0);

  // backward chain (blocks 2,3) on time-reversed h
  k_mm<0, 128><<<dim3(2, TOKn / 64), dim3(256), 0, stream>>>(
      F, WTsp, sp_b2, 128, 1, H, nullptr);
  mamba_round(2);
  mamba_round(3);
  k_gather<<<dim3(384), dim3(256), 0, stream>>>(H, XF, 128, 1);

  // tail
  k_fuse<<<dim3(768), dim3(128), 0, stream>>>(XF, fuse_w, fuse_b, FE);
  k_band<<<dim3(1152), dim3(128), 0, stream>>>(FE, band_pw, band_pb, band_emb, TO);
  k_pos<<<dim3(576), dim3(256), 0, stream>>>(TO, pos_w, pos_b, T2v);
  k_hemi<<<dim3(1152), dim3(128), 0, stream>>>(T2v, perm, hemi_w, hemi_b, FL);
  k_attn<<<dim3(128), dim3(256), 0, stream>>>(FL, a_ln_g, a_ln_b, a_w1, a_b1,
                                              a_w2, a_b2, LO);
  k_smagg<<<dim3(4), dim3(256), 0, stream>>>(FL, LO, AG);
  k_lnm<<<dim3(4), dim3(256), 0, stream>>>(AG, m_ln_g, m_ln_b, AGN);
  k_g1<<<dim3(4, 4), dim3(256), 0, stream>>>(AGN, m_w1, m_b1, G1v);
  k_f3<<<dim3(3, 4), dim3(256), 0, stream>>>(G1v, m_w2, m_b2, (float*)d_out);
}

// Round 9
// 1372.513 us; speedup vs baseline: 2.2049x; 1.2266x over previous
//
#include <hip/hip_runtime.h>

// ---------------------------------------------------------------------------
// CSBrainAlign: spectral conv -> 4 mamba blocks (fwd chain then bwd chain,
// sequential) -> fuse@6 positions -> band/pos/hemi -> attn pool -> MLP.
// EXTERNAL dtype: float32 (per reference), int32 perm. Internal acts bf16,
// residual H fp32, fuse path fp32, output fp32.
// R6: scan lane=(d,n) remap — 256us. R7: GEMM family -> MFMA bf16.
// R8: scan v6 — 4 n per thread (wave = 16 d x 4 ng): B/C via ds_read_b128,
//     2-shfl reduction, float4 dt-phase reads. 4x fewer scan waves; xdbl
//     HBM redundancy x16 -> x4 (grid 128 bc x 4 dq).
// ---------------------------------------------------------------------------

typedef unsigned short u16;
using bf16x8 = __attribute__((ext_vector_type(8))) short;
using f32x4  = __attribute__((ext_vector_type(4))) float;

#define TT    384      // sequence length N*P
#define BCn   128      // B*C
#define TOKn  49152    // BCn*TT (one chain)
#define CH3   64       // scan chunk (steps)
#define NCH3  (TT/CH3) // 6 chunks

__device__ __forceinline__ float b2f(u16 u) {
  return __uint_as_float(((unsigned)u) << 16);
}
__device__ __forceinline__ u16 f2b(float f) {
  unsigned u = __float_as_uint(f);
  u += 0x7fffu + ((u >> 16) & 1u);   // RNE
  return (u16)(u >> 16);
}
__device__ __forceinline__ float gelu_t(float x) {
  float u2 = 1.5957691216057308f * (x + 0.044715f * x * x * x);
  float e = __expf(u2);
  float th = 1.f - 2.f / (e + 1.f);
  return 0.5f * x * (1.f + th);
}
__device__ __forceinline__ float silu_f(float x) { return x / (1.f + __expf(-x)); }
__device__ __forceinline__ float softplus_f(float x) {
  return fmaxf(x, 0.f) + log1pf(__expf(-fabsf(x)));
}

__device__ __forceinline__ float block_sum(float v, float* sb) {
  #pragma unroll
  for (int m = 32; m; m >>= 1) v += __shfl_xor(v, m);
  int lane = threadIdx.x & 63, wid = threadIdx.x >> 6;
  if (lane == 0) sb[wid] = v;
  __syncthreads();
  float tot = sb[0] + sb[1] + sb[2] + sb[3];
  __syncthreads();
  return tot;
}

// ---------------------------------------------------------------------------
// MFMA GEMM: out[tok][n] = X[tok][0:KT] @ W[0:KT][n],  X bf16, WT bf16 [n][k].
// 64x64 tile, 256 thr = 4 waves, each wave 32x32 via 2x2 16x16x32 frags.
// EPI: 0 spectral -> H f32 (+bias; rev!=0 time-reversed)
//      1 W_in     -> XZ bf16 (stride 512)
//      2 W_x      -> XDBL f32 (stride 40, store n<40)
//      3 W_out    -> H += acc + bias
// ---------------------------------------------------------------------------
template <int EPI, int KT>
__global__ __launch_bounds__(256) void k_mm(
    const u16* __restrict__ X, const u16* __restrict__ WT,
    const float* __restrict__ bias, int Nw, int rev,
    float* __restrict__ o0, u16* __restrict__ ob0) {
  constexpr int AK = KT + 8;          // row pad
  __shared__ u16 As[64 * AK];
  __shared__ u16 Bs[64 * AK];
  const int tid = threadIdx.x;
  const int n0 = blockIdx.x * 64;
  const int tok0 = blockIdx.y * 64;

  constexpr int VPR = KT / 8;
  constexpr int ITER = 64 * VPR / 256;
  #pragma unroll
  for (int j = 0; j < ITER; ++j) {
    int idx = tid + j * 256;
    int row = idx / VPR, vec = idx % VPR;
    *reinterpret_cast<uint4*>(&As[row * AK + vec * 8]) =
        *reinterpret_cast<const uint4*>(&X[(size_t)(tok0 + row) * KT + vec * 8]);
    *reinterpret_cast<uint4*>(&Bs[row * AK + vec * 8]) =
        *reinterpret_cast<const uint4*>(&WT[(size_t)(n0 + row) * KT + vec * 8]);
  }
  __syncthreads();

  const int w = tid >> 6, lane = tid & 63;
  const int wm = (w & 1) * 32, wn = (w >> 1) * 32;
  const int lrow = lane & 15, quad = lane >> 4;
  f32x4 acc[2][2] = {};
  #pragma unroll
  for (int ks = 0; ks < KT / 32; ++ks) {
    int koff = ks * 32 + quad * 8;
    bf16x8 a0 = *reinterpret_cast<const bf16x8*>(&As[(wm + lrow) * AK + koff]);
    bf16x8 a1 = *reinterpret_cast<const bf16x8*>(&As[(wm + 16 + lrow) * AK + koff]);
    bf16x8 b0 = *reinterpret_cast<const bf16x8*>(&Bs[(wn + lrow) * AK + koff]);
    bf16x8 b1 = *reinterpret_cast<const bf16x8*>(&Bs[(wn + 16 + lrow) * AK + koff]);
    acc[0][0] = __builtin_amdgcn_mfma_f32_16x16x32_bf16(a0, b0, acc[0][0], 0, 0, 0);
    acc[0][1] = __builtin_amdgcn_mfma_f32_16x16x32_bf16(a0, b1, acc[0][1], 0, 0, 0);
    acc[1][0] = __builtin_amdgcn_mfma_f32_16x16x32_bf16(a1, b0, acc[1][0], 0, 0, 0);
    acc[1][1] = __builtin_amdgcn_mfma_f32_16x16x32_bf16(a1, b1, acc[1][1], 0, 0, 0);
  }

  #pragma unroll
  for (int mi = 0; mi < 2; ++mi)
    #pragma unroll
    for (int ni = 0; ni < 2; ++ni)
      #pragma unroll
      for (int r = 0; r < 4; ++r) {
        int tok = tok0 + wm + mi * 16 + quad * 4 + r;
        int n = n0 + wn + ni * 16 + lrow;
        float v = acc[mi][ni][r];
        if (EPI == 0) {
          v += bias[n];
          int bc = tok / TT, t = tok % TT;
          int tok2 = rev ? (bc * TT + (TT - 1 - t)) : tok;
          o0[(size_t)tok2 * 128 + n] = v;
        } else if (EPI == 1) {
          ob0[(size_t)tok * 512 + n] = f2b(v);
        } else if (EPI == 2) {
          if (n < 40) o0[(size_t)tok * 40 + n] = v;
        } else if (EPI == 3) {
          v += bias[n];
          o0[(size_t)tok * 128 + n] += v;
        }
      }
  (void)Nw;
}

// ---- weight prep: f32 -> bf16, transposed to [n][k] ----
__global__ __launch_bounds__(256) void k_tin(const float* __restrict__ W,
                                             u16* __restrict__ WT) {
  int i = blockIdx.x * 256 + threadIdx.x;   // 4*512*128
  int blk = i >> 16, r = i & 65535;
  int n = r >> 7, k = r & 127;
  WT[i] = f2b(W[blk * 65536 + k * 512 + n]);
}
__global__ __launch_bounds__(256) void k_tout(const float* __restrict__ W,
                                              u16* __restrict__ WT) {
  int i = blockIdx.x * 256 + threadIdx.x;   // 4*128*256
  int blk = i >> 15, r = i & 32767;
  int n = r >> 8, k = r & 255;
  WT[i] = f2b(W[blk * 32768 + k * 128 + n]);
}
__global__ __launch_bounds__(256) void k_tx(const float* __restrict__ W,
                                            u16* __restrict__ WT) {
  int i = blockIdx.x * 256 + threadIdx.x;   // 4*64*256
  int blk = i >> 14, r = i & 16383;
  int n = r >> 8, k = r & 255;
  WT[i] = (n < 40) ? f2b(W[blk * 10240 + k * 40 + n]) : 0;
}
__global__ __launch_bounds__(256) void k_tsp(const float* __restrict__ W,
                                             u16* __restrict__ WT) {
  int i = blockIdx.x * 256 + threadIdx.x;   // 128*128 ([o][c] directly)
  WT[i] = f2b(W[i]);
}

// spectral conv7 (pad 3) + bias + gelu -> F bf16 [token][c]
__global__ __launch_bounds__(128) void k_spec1(const float* __restrict__ x,
                                               const float* __restrict__ w1,
                                               const float* __restrict__ b1,
                                               u16* __restrict__ F) {
  int token = blockIdx.x;
  int c = threadIdx.x;
  int bc = token / TT, t = token % TT;
  const float* xr = x + (size_t)bc * TT;
  const float* wr = w1 + c * 7;
  float acc = b1[c];
  #pragma unroll
  for (int k = 0; k < 7; ++k) {
    int tt = t + k - 3;
    float xv = (tt >= 0 && tt < TT) ? xr[tt] : 0.f;
    acc += xv * wr[k];
  }
  F[(size_t)token * 128 + c] = f2b(gelu_t(acc));
}

// per-token LayerNorm over D=128: H f32 -> XLN bf16 (weights pre-offset)
__global__ __launch_bounds__(256) void k_ln(const float* __restrict__ H,
                                            const float* __restrict__ gg,
                                            const float* __restrict__ bb,
                                            u16* __restrict__ XLN) {
  int tid = threadIdx.x;
  int lane = tid & 63, wid = tid >> 6;
  int token = blockIdx.x * 4 + wid;
  const float* hr = H + (size_t)token * 128;
  float a = hr[lane], b = hr[lane + 64];
  float s = a + b;
  #pragma unroll
  for (int m = 32; m; m >>= 1) s += __shfl_xor(s, m);
  float mean = s * (1.f / 128.f);
  float d1 = a - mean, d2 = b - mean;
  float q = d1 * d1 + d2 * d2;
  #pragma unroll
  for (int m = 32; m; m >>= 1) q += __shfl_xor(q, m);
  float rs = rsqrtf(q * (1.f / 128.f) + 1e-5f);
  XLN[(size_t)token * 128 + lane] = f2b(d1 * rs * gg[lane] + bb[lane]);
  XLN[(size_t)token * 128 + lane + 64] =
      f2b(d2 * rs * gg[lane + 64] + bb[lane + 64]);
}

// causal depthwise conv (DC=4) + silu : XZ[:, :256] -> XC (4 chan/thread)
__global__ __launch_bounds__(256) void k_conv(const u16* __restrict__ XZ,
                                              const float* __restrict__ cw,
                                              const float* __restrict__ cb,
                                              u16* __restrict__ XC) {
  int idx = blockIdx.x * 256 + threadIdx.x;   // TOKn * 64
  int d4 = idx & 63;
  int tokg = idx >> 6;
  int t = tokg % TT;
  int dbase = d4 * 4;
  const float* cwp = cw + dbase * 4;
  float wv[4][4];
  #pragma unroll
  for (int j = 0; j < 4; ++j)
    #pragma unroll
    for (int k = 0; k < 4; ++k) wv[j][k] = cwp[j * 4 + k];
  float accv[4];
  #pragma unroll
  for (int j = 0; j < 4; ++j) accv[j] = cb[dbase + j];
  #pragma unroll
  for (int k = 0; k < 4; ++k) {
    int tt = t + k - 3;
    if (tt < 0) continue;
    ushort4 xv = *reinterpret_cast<const ushort4*>(
        &XZ[(size_t)(tokg + k - 3) * 512 + dbase]);
    u16 xa[4];
    *reinterpret_cast<ushort4*>(xa) = xv;
    #pragma unroll
    for (int j = 0; j < 4; ++j) accv[j] += b2f(xa[j]) * wv[j][k];
  }
  u16 oa[4];
  #pragma unroll
  for (int j = 0; j < 4; ++j) oa[j] = f2b(silu_f(accv[j]));
  *reinterpret_cast<ushort4*>(&XC[(size_t)tokg * 256 + dbase]) =
      *reinterpret_cast<ushort4*>(oa);
}

// ---------------------------------------------------------------------------
// selective scan v6: grid = 128 bc x 4 dq (512 blocks), 256 threads.
// Scan phase: thread owns (d, 4 n): dl = tid>>2, ng = tid&3.
// Per step: dtl b32 + xcl b16 + B float4 (b128) + C float4 + 2 shfl + ybuf.
// dt phase & epilogue: dcol = tid&63 fixed; float4 xdl reads.
// ---------------------------------------------------------------------------
__global__ __launch_bounds__(256) void k_scan(
    const float* __restrict__ XDBL, u16* __restrict__ XC,
    const u16* __restrict__ XZ, const float* __restrict__ Wdt,
    const float* __restrict__ bdt, const float* __restrict__ Alog,
    const float* __restrict__ Dpv) {
  __shared__ float xdl[CH3 * 40];    // 10 KB
  __shared__ float dtl[CH3 * 64];    // 16 KB
  __shared__ u16   xcl[CH3 * 64];    // 8 KB
  __shared__ u16   zl [CH3 * 64];    // 8 KB
  __shared__ float ybuf[CH3 * 64];   // 16 KB
  const int tid = threadIdx.x;
  const int bc = blockIdx.x >> 2, dq = blockIdx.x & 3;
  const int ng = tid & 3;            // n-group (scan)
  const int dl = tid >> 2;           // d_local (scan)
  const int dcol = tid & 63;         // d_local (dt/epilogue)

  const int d_scan = dq * 64 + dl;
  float A[4];
  #pragma unroll
  for (int j = 0; j < 4; ++j)
    A[j] = -__expf(Alog[d_scan * 16 + ng * 4 + j]);
  float wdtr[8];
  #pragma unroll
  for (int j = 0; j < 8; ++j) wdtr[j] = Wdt[j * 256 + dq * 64 + dcol];
  const float bd = bdt[dq * 64 + dcol];
  const float dpar = Dpv[dq * 64 + dcol];

  const size_t base = (size_t)bc * TT;
  const float* xdg = XDBL + base * 40;
  const uint4* xcu4 = (const uint4*)XC;
  const uint4* zu4  = (const uint4*)XZ;

  float sx[10];
  uint4 scx[2], szx[2];
  auto issue_loads = [&](int c) {
    const float* p = xdg + (size_t)c * CH3 * 40;
    #pragma unroll
    for (int k = 0; k < 10; ++k) sx[k] = p[tid + k * 256];
    #pragma unroll
    for (int k = 0; k < 2; ++k) {
      int v = tid + k * 256;           // 0..511: t = v>>3, q = v&7
      int t = v >> 3, q = v & 7;
      size_t tok = base + (size_t)c * CH3 + t;
      scx[k] = xcu4[tok * 32 + dq * 8 + q];
      szx[k] = zu4[tok * 64 + 32 + dq * 8 + q];
    }
  };
  auto write_lds = [&]() {
    #pragma unroll
    for (int k = 0; k < 10; ++k) xdl[tid + k * 256] = sx[k];
    #pragma unroll
    for (int k = 0; k < 2; ++k) {
      int v = tid + k * 256;
      ((uint4*)xcl)[v] = scx[k];
      ((uint4*)zl)[v] = szx[k];
    }
  };

  issue_loads(0);
  write_lds();
  __syncthreads();

  float hc[4] = {};
  for (int c = 0; c < NCH3; ++c) {
    if (c + 1 < NCH3) issue_loads(c + 1);
    // dt phase: 16 values/thread at fixed dcol; float4 xdl reads
    #pragma unroll
    for (int k = 0; k < 16; ++k) {
      int t = (tid >> 6) + 4 * k;
      float4 x0 = *reinterpret_cast<const float4*>(&xdl[t * 40]);
      float4 x1 = *reinterpret_cast<const float4*>(&xdl[t * 40 + 4]);
      float acc = bd;
      acc += x0.x * wdtr[0] + x0.y * wdtr[1] + x0.z * wdtr[2] + x0.w * wdtr[3];
      acc += x1.x * wdtr[4] + x1.y * wdtr[5] + x1.z * wdtr[6] + x1.w * wdtr[7];
      dtl[t * 64 + dcol] = softplus_f(acc);
    }
    __syncthreads();
    // scan phase: 64 steps, 4 n per thread
    #pragma unroll 4
    for (int t = 0; t < CH3; ++t) {
      float dtv = dtl[t * 64 + dl];
      float xcv = b2f(xcl[t * 64 + dl]);
      float4 Bv = *reinterpret_cast<const float4*>(&xdl[t * 40 + 8 + ng * 4]);
      float4 Cv = *reinterpret_cast<const float4*>(&xdl[t * 40 + 24 + ng * 4]);
      float dx = dtv * xcv;
      float e0 = __expf(A[0] * dtv);
      float e1 = __expf(A[1] * dtv);
      float e2 = __expf(A[2] * dtv);
      float e3 = __expf(A[3] * dtv);
      hc[0] = fmaf(hc[0], e0, dx * Bv.x);
      hc[1] = fmaf(hc[1], e1, dx * Bv.y);
      hc[2] = fmaf(hc[2], e2, dx * Bv.z);
      hc[3] = fmaf(hc[3], e3, dx * Bv.w);
      float yv = hc[0] * Cv.x + hc[1] * Cv.y + hc[2] * Cv.z + hc[3] * Cv.w;
      yv += __shfl_xor(yv, 1);
      yv += __shfl_xor(yv, 2);
      if (ng == 0) ybuf[t * 64 + dl] = yv;
    }
    __syncthreads();
    // epilogue: 16 values/thread at fixed dcol; coalesced store
    #pragma unroll
    for (int k = 0; k < 16; ++k) {
      int t = (tid >> 6) + 4 * k;
      int v = t * 64 + dcol;
      float y = ybuf[v];
      float xcv = b2f(xcl[v]);
      float zz = b2f(zl[v]);
      y = (y + xcv * dpar) * silu_f(zz);
      XC[(base + (size_t)c * CH3 + t) * 256 + dq * 64 + dcol] = f2b(y);
    }
    __syncthreads();
    if (c + 1 < NCH3) {
      write_lds();
      __syncthreads();
    }
  }
}

// gather the 6 needed positions into XF[768][256] f32 (half=0 fwd,128 bwd)
__global__ __launch_bounds__(256) void k_gather(const float* __restrict__ H,
                                                float* __restrict__ XF,
                                                int half, int revpos) {
  int i = blockIdx.x * 256 + threadIdx.x;   // 768*128
  int col = i & 127, row = i >> 7;
  int bc = row / 6, u = row % 6;
  int tu = 63 + 64 * u;
  int t = revpos ? (TT - 1 - tu) : tu;
  XF[(size_t)row * 256 + half + col] = H[(size_t)(bc * TT + t) * 128 + col];
}

// fuse: FE[row][d] = XF[row][:] @ fuse_w + fuse_b   (768 rows, K=256)
__global__ __launch_bounds__(128) void k_fuse(const float* __restrict__ XF,
                                              const float* __restrict__ fw,
                                              const float* __restrict__ fb,
                                              float* __restrict__ FE) {
  int row = blockIdx.x;
  int d = threadIdx.x;
  __shared__ float rows[256];
  rows[d] = XF[(size_t)row * 256 + d];
  rows[128 + d] = XF[(size_t)row * 256 + 128 + d];
  __syncthreads();
  float acc = fb[d];
  for (int k = 0; k < 256; ++k) acc += rows[k] * fw[k * 128 + d];
  FE[(size_t)row * 128 + d] = acc;
}

// band projection + event reorder: TO[(bc*9+j)][d]
__global__ __launch_bounds__(128) void k_band(const float* __restrict__ FE,
                                              const float* __restrict__ pw,
                                              const float* __restrict__ pb,
                                              const float* __restrict__ pe,
                                              float* __restrict__ TO) {
  const int u_of[9] = {0, 1, 2, 2, 3, 4, 5, 5, 5};
  const int k_of[9] = {0, 0, 0, 1, 0, 0, 0, 1, 2};
  int bid = blockIdx.x;
  int bc = bid / 9, j = bid % 9;
  int u = u_of[j], kq = k_of[j];
  __shared__ float fs[128];
  int d = threadIdx.x;
  fs[d] = FE[(size_t)(bc * 6 + u) * 128 + d];
  __syncthreads();
  float acc = pb[kq * 128 + d] + pe[kq * 128 + d];
  const float* wp = pw + kq * 16384 + d;
  for (int c = 0; c < 128; ++c) acc += fs[c] * wp[c * 128];
  TO[(size_t)bid * 128 + d] = acc;
}

// depthwise 19x7 pos conv over (C=32, L=9) + residual -> T2 [b][c][l][d]
__global__ __launch_bounds__(256) void k_pos(const float* __restrict__ TO,
                                             const float* __restrict__ pw,
                                             const float* __restrict__ pb,
                                             float* __restrict__ T2) {
  int idx = blockIdx.x * 256 + threadIdx.x;   // 147456
  int d = idx & 127;
  int l = (idx >> 7) % 9;
  int c = (idx / 1152) & 31;
  int b = idx / 36864;
  float acc = 0.f;
  const float* wd = pw + d * 133;
  for (int i = 0; i < 19; ++i) {
    int ci = c + i - 9;
    if (ci < 0 || ci >= 32) continue;
    const float* trow = TO + (size_t)(b * 32 + ci) * 9 * 128 + d;
    #pragma unroll
    for (int jj = 0; jj < 7; ++jj) {
      int lj = l + jj - 3;
      if (lj < 0 || lj >= 9) continue;
      acc += trow[lj * 128] * wd[i * 7 + jj];
    }
  }
  T2[idx] = TO[idx] + acc + pb[d];
}

// hemisphere fusion: concat(own, permuted) @ hemi_w + hemi_b -> FL (flatf)
__global__ __launch_bounds__(128) void k_hemi(const float* __restrict__ T2,
                                              const int* __restrict__ perm,
                                              const float* __restrict__ hw,
                                              const float* __restrict__ hb,
                                              float* __restrict__ FL) {
  int bid = blockIdx.x;   // b*288 + c*9 + l
  int b = bid / 288;
  int c = (bid / 9) % 32;
  int l = bid % 9;
  int pc = perm[b * 32 + c];
  __shared__ float rows[256];
  int d = threadIdx.x;
  rows[d] = T2[((size_t)(b * 32 + c) * 9 + l) * 128 + d];
  rows[128 + d] = T2[((size_t)(b * 32 + pc) * 9 + l) * 128 + d];
  __syncthreads();
  float acc = hb[d];
  for (int k = 0; k < 256; ++k) acc += rows[k] * hw[k * 128 + d];
  FL[(size_t)(b * 32 + c) * 1152 + l * 128 + d] = acc;
}

// attention logits: LN(1152) -> @a_w1(200) -> gelu -> @a_w2 -> logit
__global__ __launch_bounds__(256) void k_attn(
    const float* __restrict__ FL, const float* __restrict__ lg,
    const float* __restrict__ lb, const float* __restrict__ w1,
    const float* __restrict__ b1, const float* __restrict__ w2,
    const float* __restrict__ ab2, float* __restrict__ LO) {
  __shared__ float xn[1152];
  __shared__ float sb[4];
  int row = blockIdx.x;
  int tid = threadIdx.x;
  const float* xr = FL + (size_t)row * 1152;
  float xl[5];
  int cnt = 0;
  float s = 0.f;
  for (int i = tid; i < 1152; i += 256) { xl[cnt] = xr[i]; s += xl[cnt]; ++cnt; }
  float tot = block_sum(s, sb);
  float mean = tot * (1.f / 1152.f);
  float q = 0.f;
  for (int k = 0; k < cnt; ++k) { float dd = xl[k] - mean; q += dd * dd; }
  float qt = block_sum(q, sb);
  float rs = rsqrtf(qt * (1.f / 1152.f) + 1e-5f);
  cnt = 0;
  for (int i = tid; i < 1152; i += 256) {
    xn[i] = (xl[cnt] - mean) * rs * lg[i] + lb[i];
    ++cnt;
  }
  __syncthreads();
  float g = 0.f;
  if (tid < 200) {
    float acc = b1[tid];
    for (int i = 0; i < 1152; ++i) acc += xn[i] * w1[i * 200 + tid];
    g = gelu_t(acc);
  }
  __syncthreads();
  if (tid < 200) xn[tid] = g;
  __syncthreads();
  float s2 = (tid < 200) ? xn[tid] * w2[tid] : 0.f;
  float t2 = block_sum(s2, sb);
  if (tid == 0) LO[row] = t2 + ab2[0];
}

// softmax over C=32 + weighted aggregation of flatf -> AG[b][1152]
__global__ __launch_bounds__(256) void k_smagg(const float* __restrict__ FL,
                                               const float* __restrict__ LO,
                                               float* __restrict__ AG) {
  int b = blockIdx.x;
  int tid = threadIdx.x;
  __shared__ float w[32];
  if (tid == 0) {
    float mx = -1e30f;
    for (int c = 0; c < 32; ++c) mx = fmaxf(mx, LO[b * 32 + c]);
    float sum = 0.f;
    for (int c = 0; c < 32; ++c) { float e = __expf(LO[b * 32 + c] - mx); w[c] = e; sum += e; }
    float inv = 1.f / sum;
    for (int c = 0; c < 32; ++c) w[c] *= inv;
  }
  __syncthreads();
  for (int f = tid; f < 1152; f += 256) {
    float acc = 0.f;
    for (int c = 0; c < 32; ++c) acc += FL[(size_t)(b * 32 + c) * 1152 + f] * w[c];
    AG[b * 1152 + f] = acc;
  }
}

// final LN over agg
__global__ __launch_bounds__(256) void k_lnm(const float* __restrict__ AG,
                                             const float* __restrict__ lg,
                                             const float* __restrict__ lb,
                                             float* __restrict__ AGN) {
  __shared__ float sb[4];
  int b = blockIdx.x;
  int tid = threadIdx.x;
  const float* xr = AG + b * 1152;
  float xl[5];
  int cnt = 0;
  float s = 0.f;
  for (int i = tid; i < 1152; i += 256) { xl[cnt] = xr[i]; s += xl[cnt]; ++cnt; }
  float tot = block_sum(s, sb);
  float mean = tot * (1.f / 1152.f);
  float q = 0.f;
  for (int k = 0; k < cnt; ++k) { float dd = xl[k] - mean; q += dd * dd; }
  float qt = block_sum(q, sb);
  float rs = rsqrtf(qt * (1.f / 1152.f) + 1e-5f);
  cnt = 0;
  for (int i = tid; i < 1152; i += 256) {
    AGN[b * 1152 + i] = (xl[cnt] - mean) * rs * lg[i] + lb[i];
    ++cnt;
  }
}

// g1 = gelu(AGN @ m_w1 + m_b1), 1024 outs per b
__global__ __launch_bounds__(256) void k_g1(const float* __restrict__ AGN,
                                            const float* __restrict__ w1,
                                            const float* __restrict__ b1,
                                            float* __restrict__ G1) {
  int b = blockIdx.y;
  int j = blockIdx.x * 256 + threadIdx.x;   // 1024
  __shared__ float av[1152];
  for (int i = threadIdx.x; i < 1152; i += 256) av[i] = AGN[b * 1152 + i];
  __syncthreads();
  float acc = b1[j];
  for (int i = 0; i < 1152; ++i) acc += av[i] * w1[(size_t)i * 1024 + j];
  G1[b * 1024 + j] = gelu_t(acc);
}

// out = G1 @ m_w2 + m_b2 -> f32 d_out
__global__ __launch_bounds__(256) void k_f3(const float* __restrict__ G1,
                                            const float* __restrict__ w2,
                                            const float* __restrict__ b2v,
                                            float* __restrict__ out) {
  int b = blockIdx.y;
  int o = blockIdx.x * 256 + threadIdx.x;   // 768
  __shared__ float gv[1024];
  for (int i = threadIdx.x; i < 1024; i += 256) gv[i] = G1[b * 1024 + i];
  __syncthreads();
  float acc = b2v[o];
  for (int i = 0; i < 1024; ++i) acc += gv[i] * w2[(size_t)i * 768 + o];
  out[b * 768 + o] = acc;
}

extern "C" void kernel_launch(void* const* d_in, const int* in_sizes, int n_in,
                              void* d_out, int out_size, void* d_ws,
                              size_t ws_size, hipStream_t stream) {
  (void)in_sizes; (void)n_in; (void)out_size; (void)ws_size;
  const float* x      = (const float*)d_in[0];
  const int*   perm   = (const int*)d_in[1];
  const float* sp_w1  = (const float*)d_in[2];
  const float* sp_b1  = (const float*)d_in[3];
  const float* sp_w2  = (const float*)d_in[4];
  const float* sp_b2  = (const float*)d_in[5];
  const float* ln_g   = (const float*)d_in[6];
  const float* ln_b   = (const float*)d_in[7];
  const float* W_in   = (const float*)d_in[8];
  const float* conv_w = (const float*)d_in[9];
  const float* conv_b = (const float*)d_in[10];
  const float* W_x    = (const float*)d_in[11];
  const float* W_dt   = (const float*)d_in[12];
  const float* b_dt   = (const float*)d_in[13];
  const float* A_log  = (const float*)d_in[14];
  const float* Dp     = (const float*)d_in[15];
  const float* W_out  = (const float*)d_in[16];
  const float* b_out  = (const float*)d_in[17];
  const float* fuse_w = (const float*)d_in[18];
  const float* fuse_b = (const float*)d_in[19];
  const float* band_emb = (const float*)d_in[20];
  const float* band_pw  = (const float*)d_in[21];
  const float* band_pb  = (const float*)d_in[22];
  const float* pos_w  = (const float*)d_in[23];
  const float* pos_b  = (const float*)d_in[24];
  const float* hemi_w = (const float*)d_in[25];
  const float* hemi_b = (const float*)d_in[26];
  const float* a_ln_g = (const float*)d_in[27];
  const float* a_ln_b = (const float*)d_in[28];
  const float* a_w1   = (const float*)d_in[29];
  const float* a_b1   = (const float*)d_in[30];
  const float* a_w2   = (const float*)d_in[31];
  const float* a_b2   = (const float*)d_in[32];
  const float* m_ln_g = (const float*)d_in[33];
  const float* m_ln_b = (const float*)d_in[34];
  const float* m_w1   = (const float*)d_in[35];
  const float* m_b1   = (const float*)d_in[36];
  const float* m_w2   = (const float*)d_in[37];
  const float* m_b2   = (const float*)d_in[38];

  char* ws = (char*)d_ws;
  size_t off = 0;
  auto alloc = [&](size_t bytes) -> char* {
    char* p = ws + off;
    off += (bytes + 255) & ~(size_t)255;
    return p;
  };
  // peak ~139 MiB
  float* H    = (float*)alloc((size_t)TOKn * 128 * 4);   // 25.2M
  u16*   F    = (u16*)  alloc((size_t)TOKn * 128 * 2);   // 12.6M
  u16*   XLN  = (u16*)  alloc((size_t)TOKn * 128 * 2);   // 12.6M
  u16*   XZ   = (u16*)  alloc((size_t)TOKn * 512 * 2);   // 50.3M
  u16*   XC   = (u16*)  alloc((size_t)TOKn * 256 * 2);   // 25.2M
  float* XDBL = (float*)alloc((size_t)TOKn * 40 * 4);    // 7.9M
  u16*   WTin = (u16*)alloc(4 * 512 * 128 * 2);
  u16*   WTout= (u16*)alloc(4 * 128 * 256 * 2);
  u16*   WTx  = (u16*)alloc(4 * 64 * 256 * 2);
  u16*   WTsp = (u16*)alloc(128 * 128 * 2);
  float* XF   = (float*)alloc(768 * 256 * 4);
  float* FE   = (float*)alloc(768 * 128 * 4);
  float* TO   = (float*)alloc(1152 * 128 * 4);
  float* T2v  = (float*)alloc(147456 * 4);
  float* FL   = (float*)alloc(147456 * 4);
  float* LO   = (float*)alloc(128 * 4);
  float* AG   = (float*)alloc(4 * 1152 * 4);
  float* AGN  = (float*)alloc(4 * 1152 * 4);
  float* G1v  = (float*)alloc(4 * 1024 * 4);

  // weight prep (bf16, [n][k])
  k_tin <<<dim3(1024), dim3(256), 0, stream>>>(W_in, WTin);
  k_tout<<<dim3(512),  dim3(256), 0, stream>>>(W_out, WTout);
  k_tx  <<<dim3(256),  dim3(256), 0, stream>>>(W_x, WTx);
  k_tsp <<<dim3(64),   dim3(256), 0, stream>>>(sp_w2, WTsp);

  // spectral front-end
  k_spec1<<<dim3(TOKn), dim3(128), 0, stream>>>(x, sp_w1, sp_b1, F);

  auto mamba_round = [&](int blk) {
    k_ln<<<dim3(TOKn / 4), dim3(256), 0, stream>>>(
        H, ln_g + blk * 128, ln_b + blk * 128, XLN);
    k_mm<1, 128><<<dim3(8, TOKn / 64), dim3(256), 0, stream>>>(
        XLN, WTin + (size_t)blk * 65536, nullptr, 512, 0, nullptr, XZ);
    k_conv<<<dim3(TOKn * 64 / 256), dim3(256), 0, stream>>>(
        XZ, conv_w + blk * 1024, conv_b + blk * 256, XC);
    k_mm<2, 256><<<dim3(1, TOKn / 64), dim3(256), 0, stream>>>(
        XC, WTx + (size_t)blk * 16384, nullptr, 40, 0, XDBL, nullptr);
    k_scan<<<dim3(BCn * 4), dim3(256), 0, stream>>>(
        XDBL, XC, XZ, W_dt + blk * 2048, b_dt + blk * 256,
        A_log + blk * 4096, Dp + blk * 256);
    k_mm<3, 256><<<dim3(2, TOKn / 64), dim3(256), 0, stream>>>(
        XC, WTout + (size_t)blk * 32768, b_out + blk * 128, 128, 0,
        H, nullptr);
  };

  // forward chain (blocks 0,1)
  k_mm<0, 128><<<dim3(2, TOKn / 64), dim3(256), 0, stream>>>(
      F, WTsp, sp_b2, 128, 0, H, nullptr);
  mamba_round(0);
  mamba_round(1);
  k_gather<<<dim3(384), dim3(256), 0, stream>>>(H, XF, 0, 0);

  // backward chain (blocks 2,3) on time-reversed h
  k_mm<0, 128><<<dim3(2, TOKn / 64), dim3(256), 0, stream>>>(
      F, WTsp, sp_b2, 128, 1, H, nullptr);
  mamba_round(2);
  mamba_round(3);
  k_gather<<<dim3(384), dim3(256), 0, stream>>>(H, XF, 128, 1);

  // tail
  k_fuse<<<dim3(768), dim3(128), 0, stream>>>(XF, fuse_w, fuse_b, FE);
  k_band<<<dim3(1152), dim3(128), 0, stream>>>(FE, band_pw, band_pb, band_emb, TO);
  k_pos<<<dim3(576), dim3(256), 0, stream>>>(TO, pos_w, pos_b, T2v);
  k_hemi<<<dim3(1152), dim3(128), 0, stream>>>(T2v, perm, hemi_w, hemi_b, FL);
  k_attn<<<dim3(128), dim3(256), 0, stream>>>(FL, a_ln_g, a_ln_b, a_w1, a_b1,
                                              a_w2, a_b2, LO);
  k_smagg<<<dim3(4), dim3(256), 0, stream>>>(FL, LO, AG);
  k_lnm<<<dim3(4), dim3(256), 0, stream>>>(AG, m_ln_g, m_ln_b, AGN);
  k_g1<<<dim3(4, 4), dim3(256), 0, stream>>>(AGN, m_w1, m_b1, G1v);
  k_f3<<<dim3(3, 4), dim3(256), 0, stream>>>(G1v, m_w2, m_b2, (float*)d_out);
}

// Round 10
// 1285.979 us; speedup vs baseline: 2.3533x; 1.0673x over previous
//
#include <hip/hip_runtime.h>

// ---------------------------------------------------------------------------
// CSBrainAlign: spectral conv -> 4 mamba blocks (fwd chain then bwd chain,
// sequential) -> fuse@6 positions -> band/pos/hemi -> attn pool -> MLP.
// EXTERNAL dtype: float32 (per reference), int32 perm. Internal acts bf16,
// residual H fp32, fuse path fp32, output fp32.
// R6: scan lane=(d,n) remap. R7: GEMM family -> MFMA bf16.
// R8: scan v6 — 4 n per thread, ds_read_b128 B/C, 2-shfl reduction.
// R10: mm grids transposed (tokTile = blockIdx.x) so the 8 n-blocks of one
//      A-tile colocate on one XCD (A HBM fetch x8 -> x1); spec1 rewritten
//      LDS-staged (768 blocks); scan drops zl stage (global z in epilogue),
//      ybuf bf16.
// ---------------------------------------------------------------------------

typedef unsigned short u16;
using bf16x8 = __attribute__((ext_vector_type(8))) short;
using f32x4  = __attribute__((ext_vector_type(4))) float;

#define TT    384      // sequence length N*P
#define BCn   128      // B*C
#define TOKn  49152    // BCn*TT (one chain)
#define CH3   64       // scan chunk (steps)
#define NCH3  (TT/CH3) // 6 chunks

__device__ __forceinline__ float b2f(u16 u) {
  return __uint_as_float(((unsigned)u) << 16);
}
__device__ __forceinline__ u16 f2b(float f) {
  unsigned u = __float_as_uint(f);
  u += 0x7fffu + ((u >> 16) & 1u);   // RNE
  return (u16)(u >> 16);
}
__device__ __forceinline__ float gelu_t(float x) {
  float u2 = 1.5957691216057308f * (x + 0.044715f * x * x * x);
  float e = __expf(u2);
  float th = 1.f - 2.f / (e + 1.f);
  return 0.5f * x * (1.f + th);
}
__device__ __forceinline__ float silu_f(float x) { return x / (1.f + __expf(-x)); }
__device__ __forceinline__ float softplus_f(float x) {
  return fmaxf(x, 0.f) + log1pf(__expf(-fabsf(x)));
}

__device__ __forceinline__ float block_sum(float v, float* sb) {
  #pragma unroll
  for (int m = 32; m; m >>= 1) v += __shfl_xor(v, m);
  int lane = threadIdx.x & 63, wid = threadIdx.x >> 6;
  if (lane == 0) sb[wid] = v;
  __syncthreads();
  float tot = sb[0] + sb[1] + sb[2] + sb[3];
  __syncthreads();
  return tot;
}

// ---------------------------------------------------------------------------
// MFMA GEMM: out[tok][n] = X[tok][0:KT] @ W[0:KT][n],  X bf16, WT bf16 [n][k].
// grid = (tokTiles, nTiles): same-A blocks land on one XCD (linear%8 const).
// EPI: 0 spectral -> H f32 (+bias; rev!=0 time-reversed)
//      1 W_in     -> XZ bf16 (stride 512)
//      2 W_x      -> XDBL f32 (stride 40, store n<40)
//      3 W_out    -> H += acc + bias
// ---------------------------------------------------------------------------
template <int EPI, int KT>
__global__ __launch_bounds__(256) void k_mm(
    const u16* __restrict__ X, const u16* __restrict__ WT,
    const float* __restrict__ bias, int Nw, int rev,
    float* __restrict__ o0, u16* __restrict__ ob0) {
  constexpr int AK = KT + 8;          // row pad
  __shared__ u16 As[64 * AK];
  __shared__ u16 Bs[64 * AK];
  const int tid = threadIdx.x;
  const int tok0 = blockIdx.x * 64;   // R10: tokTile on x
  const int n0 = blockIdx.y * 64;

  constexpr int VPR = KT / 8;
  constexpr int ITER = 64 * VPR / 256;
  #pragma unroll
  for (int j = 0; j < ITER; ++j) {
    int idx = tid + j * 256;
    int row = idx / VPR, vec = idx % VPR;
    *reinterpret_cast<uint4*>(&As[row * AK + vec * 8]) =
        *reinterpret_cast<const uint4*>(&X[(size_t)(tok0 + row) * KT + vec * 8]);
    *reinterpret_cast<uint4*>(&Bs[row * AK + vec * 8]) =
        *reinterpret_cast<const uint4*>(&WT[(size_t)(n0 + row) * KT + vec * 8]);
  }
  __syncthreads();

  const int w = tid >> 6, lane = tid & 63;
  const int wm = (w & 1) * 32, wn = (w >> 1) * 32;
  const int lrow = lane & 15, quad = lane >> 4;
  f32x4 acc[2][2] = {};
  #pragma unroll
  for (int ks = 0; ks < KT / 32; ++ks) {
    int koff = ks * 32 + quad * 8;
    bf16x8 a0 = *reinterpret_cast<const bf16x8*>(&As[(wm + lrow) * AK + koff]);
    bf16x8 a1 = *reinterpret_cast<const bf16x8*>(&As[(wm + 16 + lrow) * AK + koff]);
    bf16x8 b0 = *reinterpret_cast<const bf16x8*>(&Bs[(wn + lrow) * AK + koff]);
    bf16x8 b1 = *reinterpret_cast<const bf16x8*>(&Bs[(wn + 16 + lrow) * AK + koff]);
    acc[0][0] = __builtin_amdgcn_mfma_f32_16x16x32_bf16(a0, b0, acc[0][0], 0, 0, 0);
    acc[0][1] = __builtin_amdgcn_mfma_f32_16x16x32_bf16(a0, b1, acc[0][1], 0, 0, 0);
    acc[1][0] = __builtin_amdgcn_mfma_f32_16x16x32_bf16(a1, b0, acc[1][0], 0, 0, 0);
    acc[1][1] = __builtin_amdgcn_mfma_f32_16x16x32_bf16(a1, b1, acc[1][1], 0, 0, 0);
  }

  #pragma unroll
  for (int mi = 0; mi < 2; ++mi)
    #pragma unroll
    for (int ni = 0; ni < 2; ++ni)
      #pragma unroll
      for (int r = 0; r < 4; ++r) {
        int tok = tok0 + wm + mi * 16 + quad * 4 + r;
        int n = n0 + wn + ni * 16 + lrow;
        float v = acc[mi][ni][r];
        if (EPI == 0) {
          v += bias[n];
          int bc = tok / TT, t = tok % TT;
          int tok2 = rev ? (bc * TT + (TT - 1 - t)) : tok;
          o0[(size_t)tok2 * 128 + n] = v;
        } else if (EPI == 1) {
          ob0[(size_t)tok * 512 + n] = f2b(v);
        } else if (EPI == 2) {
          if (n < 40) o0[(size_t)tok * 40 + n] = v;
        } else if (EPI == 3) {
          v += bias[n];
          o0[(size_t)tok * 128 + n] += v;
        }
      }
  (void)Nw;
}

// ---- weight prep: f32 -> bf16, transposed to [n][k] ----
__global__ __launch_bounds__(256) void k_tin(const float* __restrict__ W,
                                             u16* __restrict__ WT) {
  int i = blockIdx.x * 256 + threadIdx.x;   // 4*512*128
  int blk = i >> 16, r = i & 65535;
  int n = r >> 7, k = r & 127;
  WT[i] = f2b(W[blk * 65536 + k * 512 + n]);
}
__global__ __launch_bounds__(256) void k_tout(const float* __restrict__ W,
                                              u16* __restrict__ WT) {
  int i = blockIdx.x * 256 + threadIdx.x;   // 4*128*256
  int blk = i >> 15, r = i & 32767;
  int n = r >> 8, k = r & 255;
  WT[i] = f2b(W[blk * 32768 + k * 128 + n]);
}
__global__ __launch_bounds__(256) void k_tx(const float* __restrict__ W,
                                            u16* __restrict__ WT) {
  int i = blockIdx.x * 256 + threadIdx.x;   // 4*64*256
  int blk = i >> 14, r = i & 16383;
  int n = r >> 8, k = r & 255;
  WT[i] = (n < 40) ? f2b(W[blk * 10240 + k * 40 + n]) : 0;
}
__global__ __launch_bounds__(256) void k_tsp(const float* __restrict__ W,
                                             u16* __restrict__ WT) {
  int i = blockIdx.x * 256 + threadIdx.x;   // 128*128 ([o][c] directly)
  WT[i] = f2b(W[i]);
}

// spectral conv7 (pad 3) + bias + gelu -> F bf16 [token][c]
// R10: block per (bc, 64-token tile); x segment + weights staged in LDS.
__global__ __launch_bounds__(256) void k_spec1(const float* __restrict__ x,
                                               const float* __restrict__ w1,
                                               const float* __restrict__ b1,
                                               u16* __restrict__ F) {
  __shared__ float xs[70];
  __shared__ float wsh[128 * 7];
  __shared__ float bs[128];
  int bc = blockIdx.x / 6, tile = blockIdx.x % 6;
  int tid = threadIdx.x;
  for (int i = tid; i < 896; i += 256) wsh[i] = w1[i];
  if (tid < 128) bs[tid] = b1[tid];
  int t0 = tile * 64;
  if (tid < 70) {
    int t = t0 - 3 + tid;
    xs[tid] = (t >= 0 && t < TT) ? x[(size_t)bc * TT + t] : 0.f;
  }
  __syncthreads();
  #pragma unroll
  for (int k = 0; k < 32; ++k) {
    int idx = tid + k * 256;
    int tl = idx >> 7, c = idx & 127;
    const float* wr = &wsh[c * 7];
    float acc = bs[c];
    #pragma unroll
    for (int j = 0; j < 7; ++j) acc += xs[tl + j] * wr[j];
    F[((size_t)(bc * TT + t0 + tl)) * 128 + c] = f2b(gelu_t(acc));
  }
}

// per-token LayerNorm over D=128: H f32 -> XLN bf16 (weights pre-offset)
__global__ __launch_bounds__(256) void k_ln(const float* __restrict__ H,
                                            const float* __restrict__ gg,
                                            const float* __restrict__ bb,
                                            u16* __restrict__ XLN) {
  int tid = threadIdx.x;
  int lane = tid & 63, wid = tid >> 6;
  int token = blockIdx.x * 4 + wid;
  const float* hr = H + (size_t)token * 128;
  float a = hr[lane], b = hr[lane + 64];
  float s = a + b;
  #pragma unroll
  for (int m = 32; m; m >>= 1) s += __shfl_xor(s, m);
  float mean = s * (1.f / 128.f);
  float d1 = a - mean, d2 = b - mean;
  float q = d1 * d1 + d2 * d2;
  #pragma unroll
  for (int m = 32; m; m >>= 1) q += __shfl_xor(q, m);
  float rs = rsqrtf(q * (1.f / 128.f) + 1e-5f);
  XLN[(size_t)token * 128 + lane] = f2b(d1 * rs * gg[lane] + bb[lane]);
  XLN[(size_t)token * 128 + lane + 64] =
      f2b(d2 * rs * gg[lane + 64] + bb[lane + 64]);
}

// causal depthwise conv (DC=4) + silu : XZ[:, :256] -> XC (4 chan/thread)
__global__ __launch_bounds__(256) void k_conv(const u16* __restrict__ XZ,
                                              const float* __restrict__ cw,
                                              const float* __restrict__ cb,
                                              u16* __restrict__ XC) {
  int idx = blockIdx.x * 256 + threadIdx.x;   // TOKn * 64
  int d4 = idx & 63;
  int tokg = idx >> 6;
  int t = tokg % TT;
  int dbase = d4 * 4;
  const float* cwp = cw + dbase * 4;
  float wv[4][4];
  #pragma unroll
  for (int j = 0; j < 4; ++j)
    #pragma unroll
    for (int k = 0; k < 4; ++k) wv[j][k] = cwp[j * 4 + k];
  float accv[4];
  #pragma unroll
  for (int j = 0; j < 4; ++j) accv[j] = cb[dbase + j];
  #pragma unroll
  for (int k = 0; k < 4; ++k) {
    int tt = t + k - 3;
    if (tt < 0) continue;
    ushort4 xv = *reinterpret_cast<const ushort4*>(
        &XZ[(size_t)(tokg + k - 3) * 512 + dbase]);
    u16 xa[4];
    *reinterpret_cast<ushort4*>(xa) = xv;
    #pragma unroll
    for (int j = 0; j < 4; ++j) accv[j] += b2f(xa[j]) * wv[j][k];
  }
  u16 oa[4];
  #pragma unroll
  for (int j = 0; j < 4; ++j) oa[j] = f2b(silu_f(accv[j]));
  *reinterpret_cast<ushort4*>(&XC[(size_t)tokg * 256 + dbase]) =
      *reinterpret_cast<ushort4*>(oa);
}

// ---------------------------------------------------------------------------
// selective scan v7: grid = 128 bc x 4 dq (512 blocks), 256 threads.
// Scan phase: thread owns (d, 4 n): dl = tid>>2, ng = tid&3.
// R10: z not staged (epilogue reads coalesced global); ybuf bf16.
// ---------------------------------------------------------------------------
__global__ __launch_bounds__(256) void k_scan(
    const float* __restrict__ XDBL, u16* __restrict__ XC,
    const u16* __restrict__ XZ, const float* __restrict__ Wdt,
    const float* __restrict__ bdt, const float* __restrict__ Alog,
    const float* __restrict__ Dpv) {
  __shared__ float xdl[CH3 * 40];    // 10 KB
  __shared__ float dtl[CH3 * 64];    // 16 KB
  __shared__ u16   xcl[CH3 * 64];    // 8 KB
  __shared__ u16   ybuf[CH3 * 64];   // 8 KB (bf16)
  const int tid = threadIdx.x;
  const int bc = blockIdx.x >> 2, dq = blockIdx.x & 3;
  const int ng = tid & 3;            // n-group (scan)
  const int dl = tid >> 2;           // d_local (scan)
  const int dcol = tid & 63;         // d_local (dt/epilogue)

  const int d_scan = dq * 64 + dl;
  float A[4];
  #pragma unroll
  for (int j = 0; j < 4; ++j)
    A[j] = -__expf(Alog[d_scan * 16 + ng * 4 + j]);
  float wdtr[8];
  #pragma unroll
  for (int j = 0; j < 8; ++j) wdtr[j] = Wdt[j * 256 + dq * 64 + dcol];
  const float bd = bdt[dq * 64 + dcol];
  const float dpar = Dpv[dq * 64 + dcol];

  const size_t base = (size_t)bc * TT;
  const float* xdg = XDBL + base * 40;
  const uint4* xcu4 = (const uint4*)XC;

  float sx[10];
  uint4 scx[2];
  auto issue_loads = [&](int c) {
    const float* p = xdg + (size_t)c * CH3 * 40;
    #pragma unroll
    for (int k = 0; k < 10; ++k) sx[k] = p[tid + k * 256];
    #pragma unroll
    for (int k = 0; k < 2; ++k) {
      int v = tid + k * 256;           // 0..511: t = v>>3, q = v&7
      int t = v >> 3, q = v & 7;
      size_t tok = base + (size_t)c * CH3 + t;
      scx[k] = xcu4[tok * 32 + dq * 8 + q];
    }
  };
  auto write_lds = [&]() {
    #pragma unroll
    for (int k = 0; k < 10; ++k) xdl[tid + k * 256] = sx[k];
    #pragma unroll
    for (int k = 0; k < 2; ++k) {
      int v = tid + k * 256;
      ((uint4*)xcl)[v] = scx[k];
    }
  };

  issue_loads(0);
  write_lds();
  __syncthreads();

  float hc[4] = {};
  for (int c = 0; c < NCH3; ++c) {
    if (c + 1 < NCH3) issue_loads(c + 1);
    // dt phase: 16 values/thread at fixed dcol; float4 xdl reads
    #pragma unroll
    for (int k = 0; k < 16; ++k) {
      int t = (tid >> 6) + 4 * k;
      float4 x0 = *reinterpret_cast<const float4*>(&xdl[t * 40]);
      float4 x1 = *reinterpret_cast<const float4*>(&xdl[t * 40 + 4]);
      float acc = bd;
      acc += x0.x * wdtr[0] + x0.y * wdtr[1] + x0.z * wdtr[2] + x0.w * wdtr[3];
      acc += x1.x * wdtr[4] + x1.y * wdtr[5] + x1.z * wdtr[6] + x1.w * wdtr[7];
      dtl[t * 64 + dcol] = softplus_f(acc);
    }
    __syncthreads();
    // scan phase: 64 steps, 4 n per thread
    #pragma unroll 4
    for (int t = 0; t < CH3; ++t) {
      float dtv = dtl[t * 64 + dl];
      float xcv = b2f(xcl[t * 64 + dl]);
      float4 Bv = *reinterpret_cast<const float4*>(&xdl[t * 40 + 8 + ng * 4]);
      float4 Cv = *reinterpret_cast<const float4*>(&xdl[t * 40 + 24 + ng * 4]);
      float dx = dtv * xcv;
      float e0 = __expf(A[0] * dtv);
      float e1 = __expf(A[1] * dtv);
      float e2 = __expf(A[2] * dtv);
      float e3 = __expf(A[3] * dtv);
      hc[0] = fmaf(hc[0], e0, dx * Bv.x);
      hc[1] = fmaf(hc[1], e1, dx * Bv.y);
      hc[2] = fmaf(hc[2], e2, dx * Bv.z);
      hc[3] = fmaf(hc[3], e3, dx * Bv.w);
      float yv = hc[0] * Cv.x + hc[1] * Cv.y + hc[2] * Cv.z + hc[3] * Cv.w;
      yv += __shfl_xor(yv, 1);
      yv += __shfl_xor(yv, 2);
      if (ng == 0) ybuf[t * 64 + dl] = f2b(yv);
    }
    __syncthreads();
    // epilogue: 16 values/thread at fixed dcol; z from global (coalesced)
    #pragma unroll
    for (int k = 0; k < 16; ++k) {
      int t = (tid >> 6) + 4 * k;
      int v = t * 64 + dcol;
      size_t tok = base + (size_t)c * CH3 + t;
      float y = b2f(ybuf[v]);
      float xcv = b2f(xcl[v]);
      float zz = b2f(XZ[tok * 512 + 256 + dq * 64 + dcol]);
      y = (y + xcv * dpar) * silu_f(zz);
      XC[tok * 256 + dq * 64 + dcol] = f2b(y);
    }
    __syncthreads();
    if (c + 1 < NCH3) {
      write_lds();
      __syncthreads();
    }
  }
}

// gather the 6 needed positions into XF[768][256] f32 (half=0 fwd,128 bwd)
__global__ __launch_bounds__(256) void k_gather(const float* __restrict__ H,
                                                float* __restrict__ XF,
                                                int half, int revpos) {
  int i = blockIdx.x * 256 + threadIdx.x;   // 768*128
  int col = i & 127, row = i >> 7;
  int bc = row / 6, u = row % 6;
  int tu = 63 + 64 * u;
  int t = revpos ? (TT - 1 - tu) : tu;
  XF[(size_t)row * 256 + half + col] = H[(size_t)(bc * TT + t) * 128 + col];
}

// fuse: FE[row][d] = XF[row][:] @ fuse_w + fuse_b   (768 rows, K=256)
__global__ __launch_bounds__(128) void k_fuse(const float* __restrict__ XF,
                                              const float* __restrict__ fw,
                                              const float* __restrict__ fb,
                                              float* __restrict__ FE) {
  int row = blockIdx.x;
  int d = threadIdx.x;
  __shared__ float rows[256];
  rows[d] = XF[(size_t)row * 256 + d];
  rows[128 + d] = XF[(size_t)row * 256 + 128 + d];
  __syncthreads();
  float acc = fb[d];
  for (int k = 0; k < 256; ++k) acc += rows[k] * fw[k * 128 + d];
  FE[(size_t)row * 128 + d] = acc;
}

// band projection + event reorder: TO[(bc*9+j)][d]
__global__ __launch_bounds__(128) void k_band(const float* __restrict__ FE,
                                              const float* __restrict__ pw,
                                              const float* __restrict__ pb,
                                              const float* __restrict__ pe,
                                              float* __restrict__ TO) {
  const int u_of[9] = {0, 1, 2, 2, 3, 4, 5, 5, 5};
  const int k_of[9] = {0, 0, 0, 1, 0, 0, 0, 1, 2};
  int bid = blockIdx.x;
  int bc = bid / 9, j = bid % 9;
  int u = u_of[j], kq = k_of[j];
  __shared__ float fs[128];
  int d = threadIdx.x;
  fs[d] = FE[(size_t)(bc * 6 + u) * 128 + d];
  __syncthreads();
  float acc = pb[kq * 128 + d] + pe[kq * 128 + d];
  const float* wp = pw + kq * 16384 + d;
  for (int c = 0; c < 128; ++c) acc += fs[c] * wp[c * 128];
  TO[(size_t)bid * 128 + d] = acc;
}

// depthwise 19x7 pos conv over (C=32, L=9) + residual -> T2 [b][c][l][d]
__global__ __launch_bounds__(256) void k_pos(const float* __restrict__ TO,
                                             const float* __restrict__ pw,
                                             const float* __restrict__ pb,
                                             float* __restrict__ T2) {
  int idx = blockIdx.x * 256 + threadIdx.x;   // 147456
  int d = idx & 127;
  int l = (idx >> 7) % 9;
  int c = (idx / 1152) & 31;
  int b = idx / 36864;
  float acc = 0.f;
  const float* wd = pw + d * 133;
  for (int i = 0; i < 19; ++i) {
    int ci = c + i - 9;
    if (ci < 0 || ci >= 32) continue;
    const float* trow = TO + (size_t)(b * 32 + ci) * 9 * 128 + d;
    #pragma unroll
    for (int jj = 0; jj < 7; ++jj) {
      int lj = l + jj - 3;
      if (lj < 0 || lj >= 9) continue;
      acc += trow[lj * 128] * wd[i * 7 + jj];
    }
  }
  T2[idx] = TO[idx] + acc + pb[d];
}

// hemisphere fusion: concat(own, permuted) @ hemi_w + hemi_b -> FL (flatf)
__global__ __launch_bounds__(128) void k_hemi(const float* __restrict__ T2,
                                              const int* __restrict__ perm,
                                              const float* __restrict__ hw,
                                              const float* __restrict__ hb,
                                              float* __restrict__ FL) {
  int bid = blockIdx.x;   // b*288 + c*9 + l
  int b = bid / 288;
  int c = (bid / 9) % 32;
  int l = bid % 9;
  int pc = perm[b * 32 + c];
  __shared__ float rows[256];
  int d = threadIdx.x;
  rows[d] = T2[((size_t)(b * 32 + c) * 9 + l) * 128 + d];
  rows[128 + d] = T2[((size_t)(b * 32 + pc) * 9 + l) * 128 + d];
  __syncthreads();
  float acc = hb[d];
  for (int k = 0; k < 256; ++k) acc += rows[k] * hw[k * 128 + d];
  FL[(size_t)(b * 32 + c) * 1152 + l * 128 + d] = acc;
}

// attention logits: LN(1152) -> @a_w1(200) -> gelu -> @a_w2 -> logit
__global__ __launch_bounds__(256) void k_attn(
    const float* __restrict__ FL, const float* __restrict__ lg,
    const float* __restrict__ lb, const float* __restrict__ w1,
    const float* __restrict__ b1, const float* __restrict__ w2,
    const float* __restrict__ ab2, float* __restrict__ LO) {
  __shared__ float xn[1152];
  __shared__ float sb[4];
  int row = blockIdx.x;
  int tid = threadIdx.x;
  const float* xr = FL + (size_t)row * 1152;
  float xl[5];
  int cnt = 0;
  float s = 0.f;
  for (int i = tid; i < 1152; i += 256) { xl[cnt] = xr[i]; s += xl[cnt]; ++cnt; }
  float tot = block_sum(s, sb);
  float mean = tot * (1.f / 1152.f);
  float q = 0.f;
  for (int k = 0; k < cnt; ++k) { float dd = xl[k] - mean; q += dd * dd; }
  float qt = block_sum(q, sb);
  float rs = rsqrtf(qt * (1.f / 1152.f) + 1e-5f);
  cnt = 0;
  for (int i = tid; i < 1152; i += 256) {
    xn[i] = (xl[cnt] - mean) * rs * lg[i] + lb[i];
    ++cnt;
  }
  __syncthreads();
  float g = 0.f;
  if (tid < 200) {
    float acc = b1[tid];
    for (int i = 0; i < 1152; ++i) acc += xn[i] * w1[i * 200 + tid];
    g = gelu_t(acc);
  }
  __syncthreads();
  if (tid < 200) xn[tid] = g;
  __syncthreads();
  float s2 = (tid < 200) ? xn[tid] * w2[tid] : 0.f;
  float t2 = block_sum(s2, sb);
  if (tid == 0) LO[row] = t2 + ab2[0];
}

// softmax over C=32 + weighted aggregation of flatf -> AG[b][1152]
__global__ __launch_bounds__(256) void k_smagg(const float* __restrict__ FL,
                                               const float* __restrict__ LO,
                                               float* __restrict__ AG) {
  int b = blockIdx.x;
  int tid = threadIdx.x;
  __shared__ float w[32];
  if (tid == 0) {
    float mx = -1e30f;
    for (int c = 0; c < 32; ++c) mx = fmaxf(mx, LO[b * 32 + c]);
    float sum = 0.f;
    for (int c = 0; c < 32; ++c) { float e = __expf(LO[b * 32 + c] - mx); w[c] = e; sum += e; }
    float inv = 1.f / sum;
    for (int c = 0; c < 32; ++c) w[c] *= inv;
  }
  __syncthreads();
  for (int f = tid; f < 1152; f += 256) {
    float acc = 0.f;
    for (int c = 0; c < 32; ++c) acc += FL[(size_t)(b * 32 + c) * 1152 + f] * w[c];
    AG[b * 1152 + f] = acc;
  }
}

// final LN over agg
__global__ __launch_bounds__(256) void k_lnm(const float* __restrict__ AG,
                                             const float* __restrict__ lg,
                                             const float* __restrict__ lb,
                                             float* __restrict__ AGN) {
  __shared__ float sb[4];
  int b = blockIdx.x;
  int tid = threadIdx.x;
  const float* xr = AG + b * 1152;
  float xl[5];
  int cnt = 0;
  float s = 0.f;
  for (int i = tid; i < 1152; i += 256) { xl[cnt] = xr[i]; s += xl[cnt]; ++cnt; }
  float tot = block_sum(s, sb);
  float mean = tot * (1.f / 1152.f);
  float q = 0.f;
  for (int k = 0; k < cnt; ++k) { float dd = xl[k] - mean; q += dd * dd; }
  float qt = block_sum(q, sb);
  float rs = rsqrtf(qt * (1.f / 1152.f) + 1e-5f);
  cnt = 0;
  for (int i = tid; i < 1152; i += 256) {
    AGN[b * 1152 + i] = (xl[cnt] - mean) * rs * lg[i] + lb[i];
    ++cnt;
  }
}

// g1 = gelu(AGN @ m_w1 + m_b1), 1024 outs per b
__global__ __launch_bounds__(256) void k_g1(const float* __restrict__ AGN,
                                            const float* __restrict__ w1,
                                            const float* __restrict__ b1,
                                            float* __restrict__ G1) {
  int b = blockIdx.y;
  int j = blockIdx.x * 256 + threadIdx.x;   // 1024
  __shared__ float av[1152];
  for (int i = threadIdx.x; i < 1152; i += 256) av[i] = AGN[b * 1152 + i];
  __syncthreads();
  float acc = b1[j];
  for (int i = 0; i < 1152; ++i) acc += av[i] * w1[(size_t)i * 1024 + j];
  G1[b * 1024 + j] = gelu_t(acc);
}

// out = G1 @ m_w2 + m_b2 -> f32 d_out
__global__ __launch_bounds__(256) void k_f3(const float* __restrict__ G1,
                                            const float* __restrict__ w2,
                                            const float* __restrict__ b2v,
                                            float* __restrict__ out) {
  int b = blockIdx.y;
  int o = blockIdx.x * 256 + threadIdx.x;   // 768
  __shared__ float gv[1024];
  for (int i = threadIdx.x; i < 1024; i += 256) gv[i] = G1[b * 1024 + i];
  __syncthreads();
  float acc = b2v[o];
  for (int i = 0; i < 1024; ++i) acc += gv[i] * w2[(size_t)i * 768 + o];
  out[b * 768 + o] = acc;
}

extern "C" void kernel_launch(void* const* d_in, const int* in_sizes, int n_in,
                              void* d_out, int out_size, void* d_ws,
                              size_t ws_size, hipStream_t stream) {
  (void)in_sizes; (void)n_in; (void)out_size; (void)ws_size;
  const float* x      = (const float*)d_in[0];
  const int*   perm   = (const int*)d_in[1];
  const float* sp_w1  = (const float*)d_in[2];
  const float* sp_b1  = (const float*)d_in[3];
  const float* sp_w2  = (const float*)d_in[4];
  const float* sp_b2  = (const float*)d_in[5];
  const float* ln_g   = (const float*)d_in[6];
  const float* ln_b   = (const float*)d_in[7];
  const float* W_in   = (const float*)d_in[8];
  const float* conv_w = (const float*)d_in[9];
  const float* conv_b = (const float*)d_in[10];
  const float* W_x    = (const float*)d_in[11];
  const float* W_dt   = (const float*)d_in[12];
  const float* b_dt   = (const float*)d_in[13];
  const float* A_log  = (const float*)d_in[14];
  const float* Dp     = (const float*)d_in[15];
  const float* W_out  = (const float*)d_in[16];
  const float* b_out  = (const float*)d_in[17];
  const float* fuse_w = (const float*)d_in[18];
  const float* fuse_b = (const float*)d_in[19];
  const float* band_emb = (const float*)d_in[20];
  const float* band_pw  = (const float*)d_in[21];
  const float* band_pb  = (const float*)d_in[22];
  const float* pos_w  = (const float*)d_in[23];
  const float* pos_b  = (const float*)d_in[24];
  const float* hemi_w = (const float*)d_in[25];
  const float* hemi_b = (const float*)d_in[26];
  const float* a_ln_g = (const float*)d_in[27];
  const float* a_ln_b = (const float*)d_in[28];
  const float* a_w1   = (const float*)d_in[29];
  const float* a_b1   = (const float*)d_in[30];
  const float* a_w2   = (const float*)d_in[31];
  const float* a_b2   = (const float*)d_in[32];
  const float* m_ln_g = (const float*)d_in[33];
  const float* m_ln_b = (const float*)d_in[34];
  const float* m_w1   = (const float*)d_in[35];
  const float* m_b1   = (const float*)d_in[36];
  const float* m_w2   = (const float*)d_in[37];
  const float* m_b2   = (const float*)d_in[38];

  char* ws = (char*)d_ws;
  size_t off = 0;
  auto alloc = [&](size_t bytes) -> char* {
    char* p = ws + off;
    off += (bytes + 255) & ~(size_t)255;
    return p;
  };
  // peak ~139 MiB
  float* H    = (float*)alloc((size_t)TOKn * 128 * 4);   // 25.2M
  u16*   F    = (u16*)  alloc((size_t)TOKn * 128 * 2);   // 12.6M
  u16*   XLN  = (u16*)  alloc((size_t)TOKn * 128 * 2);   // 12.6M
  u16*   XZ   = (u16*)  alloc((size_t)TOKn * 512 * 2);   // 50.3M
  u16*   XC   = (u16*)  alloc((size_t)TOKn * 256 * 2);   // 25.2M
  float* XDBL = (float*)alloc((size_t)TOKn * 40 * 4);    // 7.9M
  u16*   WTin = (u16*)alloc(4 * 512 * 128 * 2);
  u16*   WTout= (u16*)alloc(4 * 128 * 256 * 2);
  u16*   WTx  = (u16*)alloc(4 * 64 * 256 * 2);
  u16*   WTsp = (u16*)alloc(128 * 128 * 2);
  float* XF   = (float*)alloc(768 * 256 * 4);
  float* FE   = (float*)alloc(768 * 128 * 4);
  float* TO   = (float*)alloc(1152 * 128 * 4);
  float* T2v  = (float*)alloc(147456 * 4);
  float* FL   = (float*)alloc(147456 * 4);
  float* LO   = (float*)alloc(128 * 4);
  float* AG   = (float*)alloc(4 * 1152 * 4);
  float* AGN  = (float*)alloc(4 * 1152 * 4);
  float* G1v  = (float*)alloc(4 * 1024 * 4);

  // weight prep (bf16, [n][k])
  k_tin <<<dim3(1024), dim3(256), 0, stream>>>(W_in, WTin);
  k_tout<<<dim3(512),  dim3(256), 0, stream>>>(W_out, WTout);
  k_tx  <<<dim3(256),  dim3(256), 0, stream>>>(W_x, WTx);
  k_tsp <<<dim3(64),   dim3(256), 0, stream>>>(sp_w2, WTsp);

  // spectral front-end
  k_spec1<<<dim3(BCn * 6), dim3(256), 0, stream>>>(x, sp_w1, sp_b1, F);

  auto mamba_round = [&](int blk) {
    k_ln<<<dim3(TOKn / 4), dim3(256), 0, stream>>>(
        H, ln_g + blk * 128, ln_b + blk * 128, XLN);
    k_mm<1, 128><<<dim3(TOKn / 64, 8), dim3(256), 0, stream>>>(
        XLN, WTin + (size_t)blk * 65536, nullptr, 512, 0, nullptr, XZ);
    k_conv<<<dim3(TOKn * 64 / 256), dim3(256), 0, stream>>>(
        XZ, conv_w + blk * 1024, conv_b + blk * 256, XC);
    k_mm<2, 256><<<dim3(TOKn / 64, 1), dim3(256), 0, stream>>>(
        XC, WTx + (size_t)blk * 16384, nullptr, 40, 0, XDBL, nullptr);
    k_scan<<<dim3(BCn * 4), dim3(256), 0, stream>>>(
        XDBL, XC, XZ, W_dt + blk * 2048, b_dt + blk * 256,
        A_log + blk * 4096, Dp + blk * 256);
    k_mm<3, 256><<<dim3(TOKn / 64, 2), dim3(256), 0, stream>>>(
        XC, WTout + (size_t)blk * 32768, b_out + blk * 128, 128, 0,
        H, nullptr);
  };

  // forward chain (blocks 0,1)
  k_mm<0, 128><<<dim3(TOKn / 64, 2), dim3(256), 0, stream>>>(
      F, WTsp, sp_b2, 128, 0, H, nullptr);
  mamba_round(0);
  mamba_round(1);
  k_gather<<<dim3(384), dim3(256), 0, stream>>>(H, XF, 0, 0);

  // backward chain (blocks 2,3) on time-reversed h
  k_mm<0, 128><<<dim3(TOKn / 64, 2), dim3(256), 0, stream>>>(
      F, WTsp, sp_b2, 128, 1, H, nullptr);
  mamba_round(2);
  mamba_round(3);
  k_gather<<<dim3(384), dim3(256), 0, stream>>>(H, XF, 128, 1);

  // tail
  k_fuse<<<dim3(768), dim3(128), 0, stream>>>(XF, fuse_w, fuse_b, FE);
  k_band<<<dim3(1152), dim3(128), 0, stream>>>(FE, band_pw, band_pb, band_emb, TO);
  k_pos<<<dim3(576), dim3(256), 0, stream>>>(TO, pos_w, pos_b, T2v);
  k_hemi<<<dim3(1152), dim3(128), 0, stream>>>(T2v, perm, hemi_w, hemi_b, FL);
  k_attn<<<dim3(128), dim3(256), 0, stream>>>(FL, a_ln_g, a_ln_b, a_w1, a_b1,
                                              a_w2, a_b2, LO);
  k_smagg<<<dim3(4), dim3(256), 0, stream>>>(FL, LO, AG);
  k_lnm<<<dim3(4), dim3(256), 0, stream>>>(AG, m_ln_g, m_ln_b, AGN);
  k_g1<<<dim3(4, 4), dim3(256), 0, stream>>>(AGN, m_w1, m_b1, G1v);
  k_f3<<<dim3(3, 4), dim3(256), 0, stream>>>(G1v, m_w2, m_b2, (float*)d_out);
}